// Round 1
// baseline (1771.105 us; speedup 1.0000x reference)
//
#include <hip/hip_runtime.h>

#define NEG_INF_F (-1e30f)

// ---------------------------------------------------------------------------
// Generic fp32 GEMM: C = A(MxK) @ B(KxN), K = N = 1024 fixed.
// 128x128 tile, BK=16, 256 threads, 8x8 micro-tile (split 4+4 rows/cols).
// Epilogue modes:
//   0: Q     -> C0 = val + bias0[c], C1 = val + bias1[c], scatter (b,h,t,s)
//   1: K/V   -> C0 = val, scatter (b,h,t,s)
//   2: KP    -> C0 = val, scatter (h,p,s), M = 2047
//   3: OUT   -> C0[r*1024+c] = val + bias0[c]
// ---------------------------------------------------------------------------
__global__ __launch_bounds__(256) void gemm_fused(
    const float* __restrict__ A, const float* __restrict__ B,
    float* __restrict__ C0, float* __restrict__ C1,
    const float* __restrict__ bias0, const float* __restrict__ bias1,
    int M, int mode)
{
  __shared__ __align__(16) float AsT[16][132];
  __shared__ __align__(16) float Bs[16][128];

  const int t  = threadIdx.x;
  const int tx = t & 15, ty = t >> 4;
  const int row0 = blockIdx.y * 128;
  const int col0 = blockIdx.x * 128;
  const int K = 1024, N = 1024;

  float acc[8][8];
#pragma unroll
  for (int i = 0; i < 8; ++i)
#pragma unroll
    for (int j = 0; j < 8; ++j) acc[i][j] = 0.f;

  const int a_m  = t >> 2;           // 0..63
  const int a_k  = (t << 2) & 15;    // 0,4,8,12
  const int b_kk = t >> 5;           // 0..7
  const int b_n  = (t << 2) & 127;   // 0..124 step 4

  for (int kb = 0; kb < K; kb += 16) {
#pragma unroll
    for (int it = 0; it < 2; ++it) {
      int m  = a_m + it * 64;
      int gr = row0 + m; gr = gr < M ? gr : M - 1;   // clamp for M=2047 tail
      float4 av = *reinterpret_cast<const float4*>(&A[(size_t)gr * K + kb + a_k]);
      AsT[a_k + 0][m] = av.x; AsT[a_k + 1][m] = av.y;
      AsT[a_k + 2][m] = av.z; AsT[a_k + 3][m] = av.w;
    }
#pragma unroll
    for (int it = 0; it < 2; ++it) {
      int kk = b_kk + it * 8;
      *reinterpret_cast<float4*>(&Bs[kk][b_n]) =
          *reinterpret_cast<const float4*>(&B[(size_t)(kb + kk) * N + col0 + b_n]);
    }
    __syncthreads();
#pragma unroll
    for (int k = 0; k < 16; ++k) {
      float4 a0 = *reinterpret_cast<const float4*>(&AsT[k][ty * 4]);
      float4 a1 = *reinterpret_cast<const float4*>(&AsT[k][64 + ty * 4]);
      float4 b0 = *reinterpret_cast<const float4*>(&Bs[k][tx * 4]);
      float4 b1 = *reinterpret_cast<const float4*>(&Bs[k][64 + tx * 4]);
      float a[8] = {a0.x, a0.y, a0.z, a0.w, a1.x, a1.y, a1.z, a1.w};
      float b[8] = {b0.x, b0.y, b0.z, b0.w, b1.x, b1.y, b1.z, b1.w};
#pragma unroll
      for (int i = 0; i < 8; ++i)
#pragma unroll
        for (int j = 0; j < 8; ++j)
          acc[i][j] = fmaf(a[i], b[j], acc[i][j]);
    }
    __syncthreads();
  }

#pragma unroll
  for (int i = 0; i < 8; ++i) {
    int r = row0 + ((i < 4) ? ty * 4 + i : 64 + ty * 4 + (i - 4));
    if (r >= M) continue;
#pragma unroll
    for (int jg = 0; jg < 2; ++jg) {
      int c = col0 + jg * 64 + tx * 4;   // multiple of 4; one (h, s..s+3) group
      float4 v4;
      v4.x = acc[i][jg * 4 + 0]; v4.y = acc[i][jg * 4 + 1];
      v4.z = acc[i][jg * 4 + 2]; v4.w = acc[i][jg * 4 + 3];
      if (mode == 0) {
        float4 pa4 = *reinterpret_cast<const float4*>(&bias0[c]);
        float4 pb4 = *reinterpret_cast<const float4*>(&bias1[c]);
        int bi = r >> 10, itok = r & 1023;
        int hh = c >> 6, s_ = c & 63;
        size_t o = ((size_t)(bi * 16 + hh) << 16) + (size_t)itok * 64 + s_;
        float4 qa4 = {v4.x + pa4.x, v4.y + pa4.y, v4.z + pa4.z, v4.w + pa4.w};
        float4 qb4 = {v4.x + pb4.x, v4.y + pb4.y, v4.z + pb4.z, v4.w + pb4.w};
        *reinterpret_cast<float4*>(&C0[o]) = qa4;
        *reinterpret_cast<float4*>(&C1[o]) = qb4;
      } else if (mode == 1) {
        int bi = r >> 10, itok = r & 1023;
        int hh = c >> 6, s_ = c & 63;
        size_t o = ((size_t)(bi * 16 + hh) << 16) + (size_t)itok * 64 + s_;
        *reinterpret_cast<float4*>(&C0[o]) = v4;
      } else if (mode == 2) {
        int hh = c >> 6, s_ = c & 63;
        size_t o = ((size_t)hh * 2047 + r) * 64 + s_;
        *reinterpret_cast<float4*>(&C0[o]) = v4;
      } else {
        float4 b4 = *reinterpret_cast<const float4*>(&bias0[c]);
        float4 o4 = {v4.x + b4.x, v4.y + b4.y, v4.z + b4.z, v4.w + b4.w};
        *reinterpret_cast<float4*>(&C0[(size_t)r * N + c]) = o4;
      }
    }
  }
}

// ---------------------------------------------------------------------------
// Flash-style relative attention.
//   score[i,j] = qa[i]·k[j] + qb[i]·kp[i+j], causal, online softmax, O = P@V.
// Block: 64 query rows for one (b,h). 256 threads, 4x4 micro-tile of 64x64.
// LDS: qaT/qbT persistent [s][ii] (64x68), kT chunked [s][jj] (32x68),
//      kpT chunked [s][d] (32x132) aliased with Pt[jj][ii] (64x68).
// ---------------------------------------------------------------------------
__global__ __launch_bounds__(256) void attn_kernel(
    const float* __restrict__ qa_g, const float* __restrict__ qb_g,
    const float* __restrict__ k_g,  const float* __restrict__ v_g,
    const float* __restrict__ kp_g, float* __restrict__ ctx)
{
  __shared__ __align__(16) float qaT[64][68];
  __shared__ __align__(16) float qbT[64][68];
  __shared__ __align__(16) float kT[32][68];
  __shared__ __align__(16) float kpPt[4352];   // union: kpT[32][132] / Pt[64][68]

  float (*kpT)[132] = reinterpret_cast<float (*)[132]>(kpPt);
  float (*Pt)[68]   = reinterpret_cast<float (*)[68]>(kpPt);

  const int t  = threadIdx.x;
  const int tx = t & 15, ty = t >> 4;
  const int i0 = blockIdx.x * 64;
  const int bh = blockIdx.y;           // b*16 + h
  const int h  = bh & 15;

  const float* qa_b = qa_g + ((size_t)bh << 16);
  const float* qb_b = qb_g + ((size_t)bh << 16);
  const float* k_b  = k_g  + ((size_t)bh << 16);
  const float* v_b  = v_g  + ((size_t)bh << 16);
  const float* kp_b = kp_g + (size_t)h * 2047 * 64;

  // stage qaT/qbT (transposed: [s][ii]) once per block
#pragma unroll
  for (int it = 0; it < 4; ++it) {
    int f = (t << 2) + (it << 10);
    int ii = f >> 6, s0 = f & 63;
    float4 va = *reinterpret_cast<const float4*>(&qa_b[(size_t)(i0 + ii) * 64 + s0]);
    qaT[s0 + 0][ii] = va.x; qaT[s0 + 1][ii] = va.y;
    qaT[s0 + 2][ii] = va.z; qaT[s0 + 3][ii] = va.w;
    float4 vb = *reinterpret_cast<const float4*>(&qb_b[(size_t)(i0 + ii) * 64 + s0]);
    qbT[s0 + 0][ii] = vb.x; qbT[s0 + 1][ii] = vb.y;
    qbT[s0 + 2][ii] = vb.z; qbT[s0 + 3][ii] = vb.w;
  }

  float O[4][4], m_r[4], l_r[4];
#pragma unroll
  for (int u = 0; u < 4; ++u) {
    m_r[u] = NEG_INF_F; l_r[u] = 0.f;
#pragma unroll
    for (int w = 0; w < 4; ++w) O[u][w] = 0.f;
  }

  for (int j0 = 0; j0 <= i0; j0 += 64) {
    const int pbase = i0 + j0;
    float S[4][4];
#pragma unroll
    for (int u = 0; u < 4; ++u)
#pragma unroll
      for (int w = 0; w < 4; ++w) S[u][w] = 0.f;

    for (int ch = 0; ch < 2; ++ch) {
      __syncthreads();   // protect qaT staging (1st iter) / Pt readers / kT readers
      // stage kT chunk: [s0..s0+3][jj], s in [ch*32, ch*32+32)
#pragma unroll
      for (int it = 0; it < 2; ++it) {
        int f = (t << 2) + (it << 10);
        int jj = f >> 5, s0 = f & 31;
        float4 kv = *reinterpret_cast<const float4*>(
            &k_b[(size_t)(j0 + jj) * 64 + ch * 32 + s0]);
        kT[s0 + 0][jj] = kv.x; kT[s0 + 1][jj] = kv.y;
        kT[s0 + 2][jj] = kv.z; kT[s0 + 3][jj] = kv.w;
      }
      // stage kpT chunk: 128 pos rows d, window base = i0+j0
#pragma unroll
      for (int it = 0; it < 4; ++it) {
        int f = (t << 2) + (it << 10);
        int d = f >> 5, s0 = f & 31;
        int p = pbase + d; p = p < 2047 ? p : 2046;   // only d=127 can clip (unused)
        float4 kv = *reinterpret_cast<const float4*>(
            &kp_b[(size_t)p * 64 + ch * 32 + s0]);
        kpT[s0 + 0][d] = kv.x; kpT[s0 + 1][d] = kv.y;
        kpT[s0 + 2][d] = kv.z; kpT[s0 + 3][d] = kv.w;
      }
      __syncthreads();
      const int base = (ty + tx) << 2;   // skew-diagonal base: d = base + (u+w)
#pragma unroll
      for (int s = 0; s < 32; ++s) {
        float4 a4 = *reinterpret_cast<const float4*>(&qaT[ch * 32 + s][ty * 4]);
        float4 q4 = *reinterpret_cast<const float4*>(&qbT[ch * 32 + s][ty * 4]);
        float4 b4 = *reinterpret_cast<const float4*>(&kT[s][tx * 4]);
        float4 p0 = *reinterpret_cast<const float4*>(&kpT[s][base]);
        float4 p1 = *reinterpret_cast<const float4*>(&kpT[s][base + 4]);
        float av[4] = {a4.x, a4.y, a4.z, a4.w};
        float qv[4] = {q4.x, q4.y, q4.z, q4.w};
        float bv[4] = {b4.x, b4.y, b4.z, b4.w};
        float pv[8] = {p0.x, p0.y, p0.z, p0.w, p1.x, p1.y, p1.z, p1.w};
#pragma unroll
        for (int u = 0; u < 4; ++u)
#pragma unroll
          for (int w = 0; w < 4; ++w)
            S[u][w] = fmaf(av[u], bv[w], fmaf(qv[u], pv[u + w], S[u][w]));
      }
    }

    // causal mask (only the diagonal tile is partial)
    if (j0 == i0) {
#pragma unroll
      for (int u = 0; u < 4; ++u)
#pragma unroll
        for (int w = 0; w < 4; ++w)
          if (ty * 4 + u < tx * 4 + w) S[u][w] = NEG_INF_F;
    }

    // online softmax (row groups = 16 lanes sharing ty)
    float P[4][4];
#pragma unroll
    for (int u = 0; u < 4; ++u) {
      float rmax = fmaxf(fmaxf(S[u][0], S[u][1]), fmaxf(S[u][2], S[u][3]));
#pragma unroll
      for (int msk = 1; msk < 16; msk <<= 1)
        rmax = fmaxf(rmax, __shfl_xor(rmax, msk));
      float mnew = fmaxf(m_r[u], rmax);
      float corr = __expf(m_r[u] - mnew);
      float rsum = 0.f;
#pragma unroll
      for (int w = 0; w < 4; ++w) {
        P[u][w] = __expf(S[u][w] - mnew);
        rsum += P[u][w];
      }
#pragma unroll
      for (int msk = 1; msk < 16; msk <<= 1)
        rsum += __shfl_xor(rsum, msk);
      l_r[u] = l_r[u] * corr + rsum;
      m_r[u] = mnew;
#pragma unroll
      for (int w = 0; w < 4; ++w) O[u][w] *= corr;
    }

    __syncthreads();   // all kpT reads done -> safe to overwrite with Pt
#pragma unroll
    for (int u = 0; u < 4; ++u)
#pragma unroll
      for (int w = 0; w < 4; ++w)
        Pt[tx * 4 + w][ty * 4 + u] = P[u][w];
    __syncthreads();

    // O += P @ V  (v read from global; 16KB tile lives in L1/L2)
    for (int jj = 0; jj < 64; ++jj) {
      float4 p4 = *reinterpret_cast<const float4*>(&Pt[jj][ty * 4]);
      float4 v4 = *reinterpret_cast<const float4*>(
          &v_b[(size_t)(j0 + jj) * 64 + tx * 4]);
      float pp[4] = {p4.x, p4.y, p4.z, p4.w};
      float vv[4] = {v4.x, v4.y, v4.z, v4.w};
#pragma unroll
      for (int u = 0; u < 4; ++u)
#pragma unroll
        for (int w = 0; w < 4; ++w)
          O[u][w] = fmaf(pp[u], vv[w], O[u][w]);
    }
  }

  // normalize + write ctx in (b, t, e) layout
  const int b = bh >> 4;
#pragma unroll
  for (int u = 0; u < 4; ++u) {
    float inv = 1.f / l_r[u];
    float4 o4 = {O[u][0] * inv, O[u][1] * inv, O[u][2] * inv, O[u][3] * inv};
    size_t row = (size_t)b * 1024 + i0 + ty * 4 + u;
    *reinterpret_cast<float4*>(&ctx[row * 1024 + h * 64 + tx * 4]) = o4;
  }
}

// ---------------------------------------------------------------------------
extern "C" void kernel_launch(void* const* d_in, const int* in_sizes, int n_in,
                              void* d_out, int out_size, void* d_ws, size_t ws_size,
                              hipStream_t stream) {
  const float* x       = (const float*)d_in[0];
  const float* Wq      = (const float*)d_in[1];
  const float* Wk      = (const float*)d_in[2];
  const float* Wkp     = (const float*)d_in[3];
  const float* Wv      = (const float*)d_in[4];
  const float* Wu      = (const float*)d_in[5];
  const float* bu      = (const float*)d_in[6];
  const float* parma   = (const float*)d_in[7];   // (1,h,1,s) -> flat 1024
  const float* parmb   = (const float*)d_in[8];
  const float* pos_emb = (const float*)d_in[9];   // (2047, 1024)
  float* out = (float*)d_out;

  // workspace layout (floats)
  float* ws   = (float*)d_ws;
  float* qa   = ws;                       // 4*16*1024*64 = 4194304
  float* qb   = qa + 4194304;
  float* kbuf = qb + 4194304;
  float* vbuf = kbuf + 4194304;
  float* kp   = vbuf + 4194304;           // 16*2047*64 = 2096128
  float* ctx  = kp + 2096128;             // 4194304
  // total: 23067648 floats = 92.3 MB

  dim3 blk(256);
  // q -> qa (=q+pa), qb (=q+pb), layout (b,h,t,s)
  gemm_fused<<<dim3(8, 32), blk, 0, stream>>>(x, Wq, qa, qb, parma, parmb, 4096, 0);
  // k, v -> (b,h,t,s)
  gemm_fused<<<dim3(8, 32), blk, 0, stream>>>(x, Wk, kbuf, nullptr, nullptr, nullptr, 4096, 1);
  gemm_fused<<<dim3(8, 32), blk, 0, stream>>>(x, Wv, vbuf, nullptr, nullptr, nullptr, 4096, 1);
  // kp -> (h, p, s), M = 2047
  gemm_fused<<<dim3(8, 16), blk, 0, stream>>>(pos_emb, Wkp, kp, nullptr, nullptr, nullptr, 2047, 2);
  // attention -> ctx (b, t, e)
  attn_kernel<<<dim3(16, 64), blk, 0, stream>>>(qa, qb, kbuf, vbuf, kp, ctx);
  // out = ctx @ Wu + bu
  gemm_fused<<<dim3(8, 32), blk, 0, stream>>>(ctx, Wu, out, nullptr, bu, nullptr, 4096, 3);
}

// Round 2
// 308.877 us; speedup vs baseline: 5.7340x; 5.7340x over previous
//
#include <hip/hip_runtime.h>

typedef unsigned short u16;
typedef unsigned int   u32;
using bf16x8 = __attribute__((ext_vector_type(8))) __bf16;
using f32x4  = __attribute__((ext_vector_type(4))) float;
using u16x8  = __attribute__((ext_vector_type(8))) u16;

#define NEG_INF_F (-1e30f)

__device__ __forceinline__ u16 f2bf(float f) {
  u32 u = __float_as_uint(f);
  u32 r = (u + 0x7FFFu + ((u >> 16) & 1u)) >> 16;   // RNE
  return (u16)r;
}

__device__ __forceinline__ void async_copy16(const void* g, void* lds) {
  __builtin_amdgcn_global_load_lds(
      (const __attribute__((address_space(1))) void*)g,
      (__attribute__((address_space(3))) void*)lds, 16, 0, 0);
}

// ---------------------------------------------------------------------------
// fp32 -> bf16 row-major, 4 elems/thread
// ---------------------------------------------------------------------------
__global__ __launch_bounds__(256) void cvt_bf16(const float* __restrict__ in,
                                                u16* __restrict__ out, int n4) {
  int i = blockIdx.x * 256 + threadIdx.x;
  if (i >= n4) return;
  float4 v = reinterpret_cast<const float4*>(in)[i];
  u16 o0 = f2bf(v.x), o1 = f2bf(v.y), o2 = f2bf(v.z), o3 = f2bf(v.w);
  ushort4 o = {o0, o1, o2, o3};
  reinterpret_cast<ushort4*>(out)[i] = o;
}

// ---------------------------------------------------------------------------
// fp32 W[1024][1024] -> bf16 W^T[1024][1024], 5 weights via blockIdx.z
// ---------------------------------------------------------------------------
__global__ __launch_bounds__(256) void cvt_w_tr(
    const float* __restrict__ w0, const float* __restrict__ w1,
    const float* __restrict__ w2, const float* __restrict__ w3,
    const float* __restrict__ w4,
    u16* __restrict__ o0, u16* __restrict__ o1, u16* __restrict__ o2,
    u16* __restrict__ o3, u16* __restrict__ o4) {
  __shared__ float tile[64][65];
  const float* src; u16* dst;
  switch (blockIdx.z) {
    case 0: src = w0; dst = o0; break;
    case 1: src = w1; dst = o1; break;
    case 2: src = w2; dst = o2; break;
    case 3: src = w3; dst = o3; break;
    default: src = w4; dst = o4; break;
  }
  const int tid = threadIdx.x;
  const int r0 = blockIdx.y * 64;   // k-tile
  const int c0 = blockIdx.x * 64;   // n-tile
#pragma unroll
  for (int i = 0; i < 16; ++i) {
    int lin = tid + i * 256;
    int r = lin >> 6, c = lin & 63;
    tile[r][c] = src[(size_t)(r0 + r) * 1024 + c0 + c];
  }
  __syncthreads();
#pragma unroll
  for (int i = 0; i < 16; ++i) {
    int lin = tid + i * 256;
    int n = lin >> 6, k = lin & 63;
    dst[(size_t)(c0 + n) * 1024 + r0 + k] = f2bf(tile[k][n]);
  }
}

// ---------------------------------------------------------------------------
// bf16 MFMA GEMM: C(MxN=1024) = A(Mx1024) @ W, B given as W^T (bf16).
// 128x128 tile, BK=64, 512 threads = 8 waves (2x4), global_load_lds staging.
// Epilogue modes:
//   0: qa = val+bias0[C], qb = val+bias1[C] -> bf16 scatter (b,h,t,s)
//   1: k/v -> bf16 scatter (b,h,t,s)
//   2: kp  -> bf16 scatter (h,p,s), M=2047
//   3: out -> fp32 row-major val+bias0[C]
// ---------------------------------------------------------------------------
__global__ __launch_bounds__(512, 2) void gemm_bf16(
    const u16* __restrict__ A, const u16* __restrict__ Bt,
    float* __restrict__ outF, u16* __restrict__ out0, u16* __restrict__ out1,
    const float* __restrict__ bias0, const float* __restrict__ bias1,
    int M, int mode) {
  __shared__ u16 As[128 * 64];
  __shared__ u16 Bs[128 * 64];
  const int tid = threadIdx.x;
  const int w = tid >> 6, l = tid & 63;
  const int lg = l >> 4, lc = l & 15;
  const int wr = w >> 2, wc = w & 3;         // wave quadrant 2x4, each 64x32
  const int row0 = blockIdx.y * 128;
  const int col0 = blockIdx.x * 128;

  f32x4 acc[4][2];
#pragma unroll
  for (int fi = 0; fi < 4; ++fi)
#pragma unroll
    for (int fj = 0; fj < 2; ++fj) acc[fi][fj] = (f32x4){0.f, 0.f, 0.f, 0.f};

  for (int kb = 0; kb < 1024; kb += 64) {
#pragma unroll
    for (int it2 = 0; it2 < 2; ++it2) {
      int seg = w * 2 + it2;                 // 0..15, 8 rows (128B) each
      int r = seg * 8 + (l >> 3);
      int c8 = (l & 7) * 8;                  // bf16 col, 16B chunk
      int gr = row0 + r; if (gr > M - 1) gr = M - 1;
      async_copy16(&A[(size_t)gr * 1024 + kb + c8], &As[seg * 512]);
      async_copy16(&Bt[(size_t)(col0 + r) * 1024 + kb + c8], &Bs[seg * 512]);
    }
    __syncthreads();
#pragma unroll
    for (int ks = 0; ks < 2; ++ks) {
      bf16x8 af[4], bfr[2];
#pragma unroll
      for (int fi = 0; fi < 4; ++fi)
        af[fi] = *reinterpret_cast<const bf16x8*>(
            &As[(wr * 64 + fi * 16 + lc) * 64 + ks * 32 + lg * 8]);
#pragma unroll
      for (int fj = 0; fj < 2; ++fj)
        bfr[fj] = *reinterpret_cast<const bf16x8*>(
            &Bs[(wc * 32 + fj * 16 + lc) * 64 + ks * 32 + lg * 8]);
#pragma unroll
      for (int fi = 0; fi < 4; ++fi)
#pragma unroll
        for (int fj = 0; fj < 2; ++fj)
          acc[fi][fj] = __builtin_amdgcn_mfma_f32_16x16x32_bf16(
              af[fi], bfr[fj], acc[fi][fj], 0, 0, 0);
    }
    __syncthreads();
  }

#pragma unroll
  for (int fi = 0; fi < 4; ++fi)
#pragma unroll
    for (int fj = 0; fj < 2; ++fj)
#pragma unroll
      for (int reg = 0; reg < 4; ++reg) {
        int R = row0 + wr * 64 + fi * 16 + lg * 4 + reg;
        int C = col0 + wc * 32 + fj * 16 + lc;
        float val = acc[fi][fj][reg];
        if (mode == 3) {
          outF[(size_t)R * 1024 + C] = val + bias0[C];
        } else if (mode == 2) {
          if (R < 2047) {
            int hh = C >> 6, ss = C & 63;
            out0[((size_t)hh * 2047 + R) * 64 + ss] = f2bf(val);
          }
        } else {
          int bi = R >> 10, tt = R & 1023, hh = C >> 6, ss = C & 63;
          size_t o = ((size_t)(bi * 16 + hh) << 16) + (size_t)tt * 64 + ss;
          if (mode == 0) {
            out0[o] = f2bf(val + bias0[C]);
            out1[o] = f2bf(val + bias1[C]);
          } else {
            out0[o] = f2bf(val);
          }
        }
      }
}

// ---------------------------------------------------------------------------
// MFMA flash attention: score[i,j] = qa[i]·k[j] + qb[i]·kp[i+j], causal.
// Block = (bh, 64-query tile). 256 threads / 4 waves; wave w owns rows w*16..+15.
// Per 64-key tile: S via mfma(qa, k^T); banded term via per-wave G=qb·kp_win^T
// (5 col-frags, 16x80), G->LDS, skew gather G[r][r+c]; online softmax; PV via
// LDS-transposed V. 3 barriers/tile. LDS 57344B -> 2 blocks/CU.
// ---------------------------------------------------------------------------
__global__ __launch_bounds__(256, 2) void attn_mfma(
    const u16* __restrict__ qa_g, const u16* __restrict__ qb_g,
    const u16* __restrict__ k_g, const u16* __restrict__ v_g,
    const u16* __restrict__ kp_g, u16* __restrict__ ctx) {
  __shared__ u16 kP[64 * 72];      // k tile, later aliased as P (bf16)
  __shared__ u16 vT[64 * 72];      // v transposed [s][j]
  __shared__ u16 kpl[128 * 72];    // kp window [d][s]
  __shared__ float G[4][16 * 80];  // per-wave banded scores, stride 80

  const int tid = threadIdx.x;
  const int w = tid >> 6, l = tid & 63;
  const int lg = l >> 4, lc = l & 15;
  const int bh = blockIdx.x;
  const int h = bh & 15;
  const int i0 = (15 - (int)blockIdx.y) * 64;   // longest blocks first
  const size_t bhOff = (size_t)bh << 16;
  const size_t hOff = (size_t)h * 2047 * 64;

  // persistent A-fragments: qa/qb rows i0 + w*16 + lc
  bf16x8 qaf[2], qbf[2];
#pragma unroll
  for (int ks = 0; ks < 2; ++ks) {
    size_t o = bhOff + (size_t)(i0 + w * 16 + lc) * 64 + ks * 32 + lg * 8;
    qaf[ks] = *reinterpret_cast<const bf16x8*>(&qa_g[o]);
    qbf[ks] = *reinterpret_cast<const bf16x8*>(&qb_g[o]);
  }

  f32x4 O[4];
  float m_r[4], l_r[4];
#pragma unroll
  for (int fj = 0; fj < 4; ++fj) O[fj] = (f32x4){0.f, 0.f, 0.f, 0.f};
#pragma unroll
  for (int reg = 0; reg < 4; ++reg) { m_r[reg] = NEG_INF_F; l_r[reg] = 0.f; }

  const int nt = i0 >> 6;
  for (int jt = 0; jt <= nt; ++jt) {
    const int j0 = jt * 64;
    const int pbase = i0 + j0;
    __syncthreads();   // prev PV reads done -> restage
    // stage k [j][s]
#pragma unroll
    for (int rep = 0; rep < 2; ++rep) {
      int idx = tid + rep * 256;
      int jj = idx >> 3, c8 = (idx & 7) * 8;
      *reinterpret_cast<u16x8*>(&kP[jj * 72 + c8]) =
          *reinterpret_cast<const u16x8*>(&k_g[bhOff + (size_t)(j0 + jj) * 64 + c8]);
    }
    // stage vT [s][j] (transpose; contiguous-j scalar writes are conflict-free)
    {
      int j = tid & 63, s0 = (tid >> 6) * 16;
      u16x8 r0 = *reinterpret_cast<const u16x8*>(&v_g[bhOff + (size_t)(j0 + j) * 64 + s0]);
      u16x8 r1 = *reinterpret_cast<const u16x8*>(&v_g[bhOff + (size_t)(j0 + j) * 64 + s0 + 8]);
#pragma unroll
      for (int i2 = 0; i2 < 8; ++i2) vT[(s0 + i2) * 72 + j] = r0[i2];
#pragma unroll
      for (int i2 = 0; i2 < 8; ++i2) vT[(s0 + 8 + i2) * 72 + j] = r1[i2];
    }
    // stage kp window [d][s], d = 0..127, pos = pbase+d
#pragma unroll
    for (int rep = 0; rep < 4; ++rep) {
      int idx = tid + rep * 256;
      int d = idx >> 3, c8 = (idx & 7) * 8;
      int p = pbase + d; if (p > 2046) p = 2046;   // d=127 can clip; unused
      *reinterpret_cast<u16x8*>(&kpl[d * 72 + c8]) =
          *reinterpret_cast<const u16x8*>(&kp_g[hOff + (size_t)p * 64 + c8]);
    }
    __syncthreads();

    f32x4 S[4], Gf[5];
#pragma unroll
    for (int fj = 0; fj < 4; ++fj) S[fj] = (f32x4){0.f, 0.f, 0.f, 0.f};
#pragma unroll
    for (int fg = 0; fg < 5; ++fg) Gf[fg] = (f32x4){0.f, 0.f, 0.f, 0.f};
#pragma unroll
    for (int ks = 0; ks < 2; ++ks) {
#pragma unroll
      for (int fj = 0; fj < 4; ++fj) {
        bf16x8 kf = *reinterpret_cast<const bf16x8*>(
            &kP[(fj * 16 + lc) * 72 + ks * 32 + lg * 8]);
        S[fj] = __builtin_amdgcn_mfma_f32_16x16x32_bf16(qaf[ks], kf, S[fj], 0, 0, 0);
      }
#pragma unroll
      for (int fg = 0; fg < 5; ++fg) {
        bf16x8 pf = *reinterpret_cast<const bf16x8*>(
            &kpl[((w + fg) * 16 + lc) * 72 + ks * 32 + lg * 8]);
        Gf[fg] = __builtin_amdgcn_mfma_f32_16x16x32_bf16(qbf[ks], pf, Gf[fg], 0, 0, 0);
      }
    }
    // write per-wave G: rows rf=lg*4+reg, local cols d-w*16 = fg*16+lc (0..79)
    float* Gw = G[w];
#pragma unroll
    for (int fg = 0; fg < 5; ++fg)
#pragma unroll
      for (int reg = 0; reg < 4; ++reg)
        Gw[(lg * 4 + reg) * 80 + fg * 16 + lc] = Gf[fg][reg];
    asm volatile("s_waitcnt lgkmcnt(0)" ::: "memory");
    __builtin_amdgcn_sched_barrier(0);
    // skew gather: S[r][c] += G[r][r+c]; causal mask on diagonal tile
#pragma unroll
    for (int fj = 0; fj < 4; ++fj)
#pragma unroll
      for (int reg = 0; reg < 4; ++reg) {
        int rf = lg * 4 + reg;
        float sv = S[fj][reg] + Gw[rf * 80 + rf + fj * 16 + lc];
        if (j0 == i0 && (w * 16 + rf) < (fj * 16 + lc)) sv = NEG_INF_F;
        S[fj][reg] = sv;
      }
    // online softmax (rows live in 16-lane groups sharing lg)
#pragma unroll
    for (int reg = 0; reg < 4; ++reg) {
      float mx = fmaxf(fmaxf(S[0][reg], S[1][reg]), fmaxf(S[2][reg], S[3][reg]));
      mx = fmaxf(mx, __shfl_xor(mx, 1));
      mx = fmaxf(mx, __shfl_xor(mx, 2));
      mx = fmaxf(mx, __shfl_xor(mx, 4));
      mx = fmaxf(mx, __shfl_xor(mx, 8));
      float mnew = fmaxf(m_r[reg], mx);
      float corr = __expf(m_r[reg] - mnew);
      float rs = 0.f;
#pragma unroll
      for (int fj = 0; fj < 4; ++fj) {
        float p = __expf(S[fj][reg] - mnew);
        S[fj][reg] = p;
        rs += p;
      }
      rs += __shfl_xor(rs, 1); rs += __shfl_xor(rs, 2);
      rs += __shfl_xor(rs, 4); rs += __shfl_xor(rs, 8);
      l_r[reg] = l_r[reg] * corr + rs;
      m_r[reg] = mnew;
#pragma unroll
      for (int fj = 0; fj < 4; ++fj) O[fj][reg] *= corr;
    }
    __syncthreads();   // all waves past k-tile MFMA reads -> overwrite kP with P
#pragma unroll
    for (int fj = 0; fj < 4; ++fj)
#pragma unroll
      for (int reg = 0; reg < 4; ++reg)
        kP[(w * 16 + lg * 4 + reg) * 72 + fj * 16 + lc] = f2bf(S[fj][reg]);
    asm volatile("s_waitcnt lgkmcnt(0)" ::: "memory");
    __builtin_amdgcn_sched_barrier(0);
    // PV: O += P @ V   (A = own P rows, B from vT)
#pragma unroll
    for (int ks = 0; ks < 2; ++ks) {
      bf16x8 pa = *reinterpret_cast<const bf16x8*>(
          &kP[(w * 16 + lc) * 72 + ks * 32 + lg * 8]);
#pragma unroll
      for (int fj = 0; fj < 4; ++fj) {
        bf16x8 vb = *reinterpret_cast<const bf16x8*>(
            &vT[(fj * 16 + lc) * 72 + ks * 32 + lg * 8]);
        O[fj] = __builtin_amdgcn_mfma_f32_16x16x32_bf16(pa, vb, O[fj], 0, 0, 0);
      }
    }
  }

  // normalize + write ctx (b, t, e) as bf16
  const int b = bh >> 4;
#pragma unroll
  for (int reg = 0; reg < 4; ++reg) {
    float inv = 1.f / l_r[reg];
    int r = w * 16 + lg * 4 + reg;
#pragma unroll
    for (int fj = 0; fj < 4; ++fj)
      ctx[((size_t)b * 1024 + i0 + r) * 1024 + h * 64 + fj * 16 + lc] =
          f2bf(O[fj][reg] * inv);
  }
}

// ---------------------------------------------------------------------------
extern "C" void kernel_launch(void* const* d_in, const int* in_sizes, int n_in,
                              void* d_out, int out_size, void* d_ws, size_t ws_size,
                              hipStream_t stream) {
  const float* x       = (const float*)d_in[0];
  const float* Wq      = (const float*)d_in[1];
  const float* Wk      = (const float*)d_in[2];
  const float* Wkp     = (const float*)d_in[3];
  const float* Wv      = (const float*)d_in[4];
  const float* Wu      = (const float*)d_in[5];
  const float* bu      = (const float*)d_in[6];
  const float* parma   = (const float*)d_in[7];   // flat (h*s) = 1024
  const float* parmb   = (const float*)d_in[8];
  const float* pos_emb = (const float*)d_in[9];   // (2047, 1024)
  float* out = (float*)d_out;

  // workspace (u16 elements)
  u16* W = (u16*)d_ws;
  u16* x_bf   = W;                      // 4194304
  u16* pos_bf = x_bf + 4194304;         // 2096128
  u16* wqT    = pos_bf + 2096128;       // 1048576 each
  u16* wkT    = wqT + 1048576;
  u16* wkpT   = wkT + 1048576;
  u16* wvT    = wkpT + 1048576;
  u16* wuT    = wvT + 1048576;
  u16* qa     = wuT + 1048576;          // 4194304 (b,h,t,s)
  u16* qb     = qa + 4194304;
  u16* kb     = qb + 4194304;
  u16* vb     = kb + 4194304;
  u16* kp     = vb + 4194304;           // 2096128 (h,p,s)
  u16* ctx    = kp + 2096128;           // 4194304 (b,t,e)
  // total 35,600,960 u16 = 71.2 MB

  // conversions
  cvt_bf16<<<4096, 256, 0, stream>>>(x, x_bf, 1048576);
  cvt_bf16<<<2047, 256, 0, stream>>>(pos_emb, pos_bf, 524032);
  cvt_w_tr<<<dim3(16, 16, 5), 256, 0, stream>>>(Wq, Wk, Wkp, Wv, Wu,
                                                wqT, wkT, wkpT, wvT, wuT);
  // projections
  gemm_bf16<<<dim3(8, 32), 512, 0, stream>>>(x_bf, wqT, nullptr, qa, qb,
                                             parma, parmb, 4096, 0);
  gemm_bf16<<<dim3(8, 32), 512, 0, stream>>>(x_bf, wkT, nullptr, kb, nullptr,
                                             nullptr, nullptr, 4096, 1);
  gemm_bf16<<<dim3(8, 32), 512, 0, stream>>>(x_bf, wvT, nullptr, vb, nullptr,
                                             nullptr, nullptr, 4096, 1);
  gemm_bf16<<<dim3(8, 16), 512, 0, stream>>>(pos_bf, wkpT, nullptr, kp, nullptr,
                                             nullptr, nullptr, 2047, 2);
  // attention
  attn_mfma<<<dim3(64, 16), 256, 0, stream>>>(qa, qb, kb, vb, kp, ctx);
  // output projection (fp32 out + bias)
  gemm_bf16<<<dim3(8, 32), 512, 0, stream>>>(ctx, wuT, out, nullptr, nullptr,
                                             bu, nullptr, 4096, 3);
}

// Round 7
// 252.778 us; speedup vs baseline: 7.0066x; 1.2219x over previous
//
#include <hip/hip_runtime.h>

typedef unsigned short u16;
typedef unsigned int   u32;
using bf16x8 = __attribute__((ext_vector_type(8))) __bf16;
using f32x4  = __attribute__((ext_vector_type(4))) float;
using u16x8  = __attribute__((ext_vector_type(8))) u16;

#define NEG_INF_F (-1e30f)

__device__ __forceinline__ u16 f2bf(float f) {
  u32 u = __float_as_uint(f);
  u32 r = (u + 0x7FFFu + ((u >> 16) & 1u)) >> 16;   // RNE
  return (u16)r;
}

__device__ __forceinline__ void async_copy16(const void* g, void* lds) {
  __builtin_amdgcn_global_load_lds(
      (const __attribute__((address_space(1))) void*)g,
      (__attribute__((address_space(3))) void*)lds, 16, 0, 0);
}

// ---------------------------------------------------------------------------
// fp32 -> bf16 row-major, 4 elems/thread
// ---------------------------------------------------------------------------
__global__ __launch_bounds__(256) void cvt_bf16(const float* __restrict__ in,
                                                u16* __restrict__ out, int n4) {
  int i = blockIdx.x * 256 + threadIdx.x;
  if (i >= n4) return;
  float4 v = reinterpret_cast<const float4*>(in)[i];
  u16 o0 = f2bf(v.x), o1 = f2bf(v.y), o2 = f2bf(v.z), o3 = f2bf(v.w);
  ushort4 o = {o0, o1, o2, o3};
  reinterpret_cast<ushort4*>(out)[i] = o;
}

// ---------------------------------------------------------------------------
// fp32 W[1024][1024] -> bf16 W^T[1024][1024], 5 weights via blockIdx.z
// ---------------------------------------------------------------------------
__global__ __launch_bounds__(256) void cvt_w_tr(
    const float* __restrict__ w0, const float* __restrict__ w1,
    const float* __restrict__ w2, const float* __restrict__ w3,
    const float* __restrict__ w4,
    u16* __restrict__ o0, u16* __restrict__ o1, u16* __restrict__ o2,
    u16* __restrict__ o3, u16* __restrict__ o4) {
  __shared__ float tile[64][65];
  const float* src; u16* dst;
  switch (blockIdx.z) {
    case 0: src = w0; dst = o0; break;
    case 1: src = w1; dst = o1; break;
    case 2: src = w2; dst = o2; break;
    case 3: src = w3; dst = o3; break;
    default: src = w4; dst = o4; break;
  }
  const int tid = threadIdx.x;
  const int r0 = blockIdx.y * 64;   // k-tile
  const int c0 = blockIdx.x * 64;   // n-tile
#pragma unroll
  for (int i = 0; i < 16; ++i) {
    int lin = tid + i * 256;
    int r = lin >> 6, c = lin & 63;
    tile[r][c] = src[(size_t)(r0 + r) * 1024 + c0 + c];
  }
  __syncthreads();
#pragma unroll
  for (int i = 0; i < 16; ++i) {
    int lin = tid + i * 256;
    int n = lin >> 6, k = lin & 63;
    dst[(size_t)(c0 + n) * 1024 + r0 + k] = f2bf(tile[k][n]);
  }
}

// ---------------------------------------------------------------------------
// Fused QKV + KP projection GEMM. grid (32, 32):
//   bx in [0,24):  C = x_bf(4096x1024) @ [Wq|Wk|Wv]  (N=3072, BtQKV rows)
//   bx in [24,32): C = pos_bf(2047x1024) @ Wkp       (by<16 only)
// 128x128 tile, BK=64, 512 thr / 8 waves, global_load_lds staging.
// Epilogues scatter to (b,h,t,s) [qa=+pa, qb=+pb, k, v] or (h,p,s) [kp], bf16.
// ---------------------------------------------------------------------------
__global__ __launch_bounds__(512, 2) void gemm_qkvp(
    const u16* __restrict__ x_bf, const u16* __restrict__ pos_bf,
    const u16* __restrict__ BtQKV, const u16* __restrict__ BtKP,
    u16* __restrict__ qa, u16* __restrict__ qb, u16* __restrict__ kb,
    u16* __restrict__ vb, u16* __restrict__ kp,
    const float* __restrict__ parma, const float* __restrict__ parmb) {
  const int bx = blockIdx.x, by = blockIdx.y;
  const bool isKP = bx >= 24;
  if (isKP && by >= 16) return;

  __shared__ u16 As[128 * 64];
  __shared__ u16 Bs[128 * 64];
  const int tid = threadIdx.x;
  const int w = tid >> 6, l = tid & 63;
  const int lg = l >> 4, lc = l & 15;
  const int wr = w >> 2, wc = w & 3;
  const u16* A  = isKP ? pos_bf : x_bf;
  const u16* Bt = isKP ? BtKP : BtQKV;
  const int M = isKP ? 2047 : 4096;
  const int row0 = by * 128;
  const int col0 = (isKP ? (bx - 24) : bx) * 128;

  f32x4 acc[4][2];
#pragma unroll
  for (int fi = 0; fi < 4; ++fi)
#pragma unroll
    for (int fj = 0; fj < 2; ++fj) acc[fi][fj] = (f32x4){0.f, 0.f, 0.f, 0.f};

  for (int kbk = 0; kbk < 1024; kbk += 64) {
#pragma unroll
    for (int it2 = 0; it2 < 2; ++it2) {
      int seg = w * 2 + it2;
      int r = seg * 8 + (l >> 3);
      int c8 = (l & 7) * 8;
      int gr = row0 + r; if (gr > M - 1) gr = M - 1;
      async_copy16(&A[(size_t)gr * 1024 + kbk + c8], &As[seg * 512]);
      async_copy16(&Bt[(size_t)(col0 + r) * 1024 + kbk + c8], &Bs[seg * 512]);
    }
    __syncthreads();
#pragma unroll
    for (int ks = 0; ks < 2; ++ks) {
      bf16x8 af[4], bfr[2];
#pragma unroll
      for (int fi = 0; fi < 4; ++fi)
        af[fi] = *reinterpret_cast<const bf16x8*>(
            &As[(wr * 64 + fi * 16 + lc) * 64 + ks * 32 + lg * 8]);
#pragma unroll
      for (int fj = 0; fj < 2; ++fj)
        bfr[fj] = *reinterpret_cast<const bf16x8*>(
            &Bs[(wc * 32 + fj * 16 + lc) * 64 + ks * 32 + lg * 8]);
#pragma unroll
      for (int fi = 0; fi < 4; ++fi)
#pragma unroll
        for (int fj = 0; fj < 2; ++fj)
          acc[fi][fj] = __builtin_amdgcn_mfma_f32_16x16x32_bf16(
              af[fi], bfr[fj], acc[fi][fj], 0, 0, 0);
    }
    __syncthreads();
  }

#pragma unroll
  for (int fi = 0; fi < 4; ++fi)
#pragma unroll
    for (int fj = 0; fj < 2; ++fj)
#pragma unroll
      for (int reg = 0; reg < 4; ++reg) {
        int R = row0 + wr * 64 + fi * 16 + lg * 4 + reg;
        int C = col0 + wc * 32 + fj * 16 + lc;
        float val = acc[fi][fj][reg];
        if (isKP) {
          if (R < 2047) {
            int hh = C >> 6, ss = C & 63;
            kp[((size_t)hh * 2047 + R) * 64 + ss] = f2bf(val);
          }
        } else {
          int wsel = C >> 10, Cl = C & 1023;
          int bi = R >> 10, tt = R & 1023, hh = Cl >> 6, ss = Cl & 63;
          size_t o = ((size_t)(bi * 16 + hh) << 16) + (size_t)tt * 64 + ss;
          if (wsel == 0) {
            qa[o] = f2bf(val + parma[Cl]);
            qb[o] = f2bf(val + parmb[Cl]);
          } else if (wsel == 1) {
            kb[o] = f2bf(val);
          } else {
            vb[o] = f2bf(val);
          }
        }
      }
}

// ---------------------------------------------------------------------------
// Output projection: out(4096x1024 fp32) = ctx @ Wu + bu. Same structure.
// ---------------------------------------------------------------------------
__global__ __launch_bounds__(512, 2) void gemm_out(
    const u16* __restrict__ A, const u16* __restrict__ Bt,
    float* __restrict__ outF, const float* __restrict__ bias) {
  __shared__ u16 As[128 * 64];
  __shared__ u16 Bs[128 * 64];
  const int tid = threadIdx.x;
  const int w = tid >> 6, l = tid & 63;
  const int lg = l >> 4, lc = l & 15;
  const int wr = w >> 2, wc = w & 3;
  const int row0 = blockIdx.y * 128;
  const int col0 = blockIdx.x * 128;

  f32x4 acc[4][2];
#pragma unroll
  for (int fi = 0; fi < 4; ++fi)
#pragma unroll
    for (int fj = 0; fj < 2; ++fj) acc[fi][fj] = (f32x4){0.f, 0.f, 0.f, 0.f};

  for (int kbk = 0; kbk < 1024; kbk += 64) {
#pragma unroll
    for (int it2 = 0; it2 < 2; ++it2) {
      int seg = w * 2 + it2;
      int r = seg * 8 + (l >> 3);
      int c8 = (l & 7) * 8;
      async_copy16(&A[(size_t)(row0 + r) * 1024 + kbk + c8], &As[seg * 512]);
      async_copy16(&Bt[(size_t)(col0 + r) * 1024 + kbk + c8], &Bs[seg * 512]);
    }
    __syncthreads();
#pragma unroll
    for (int ks = 0; ks < 2; ++ks) {
      bf16x8 af[4], bfr[2];
#pragma unroll
      for (int fi = 0; fi < 4; ++fi)
        af[fi] = *reinterpret_cast<const bf16x8*>(
            &As[(wr * 64 + fi * 16 + lc) * 64 + ks * 32 + lg * 8]);
#pragma unroll
      for (int fj = 0; fj < 2; ++fj)
        bfr[fj] = *reinterpret_cast<const bf16x8*>(
            &Bs[(wc * 32 + fj * 16 + lc) * 64 + ks * 32 + lg * 8]);
#pragma unroll
      for (int fi = 0; fi < 4; ++fi)
#pragma unroll
        for (int fj = 0; fj < 2; ++fj)
          acc[fi][fj] = __builtin_amdgcn_mfma_f32_16x16x32_bf16(
              af[fi], bfr[fj], acc[fi][fj], 0, 0, 0);
    }
    __syncthreads();
  }

#pragma unroll
  for (int fi = 0; fi < 4; ++fi)
#pragma unroll
    for (int fj = 0; fj < 2; ++fj)
#pragma unroll
      for (int reg = 0; reg < 4; ++reg) {
        int R = row0 + wr * 64 + fi * 16 + lg * 4 + reg;
        int C = col0 + wc * 32 + fj * 16 + lc;
        outF[(size_t)R * 1024 + C] = acc[fi][fj][reg] + bias[C];
      }
}

// ---------------------------------------------------------------------------
// MFMA flash attention, QBLK=128 / 8 waves / KBLK=64.
// score[i,j] = qa[i]·k[j] + qb[i]·kp[i+j], causal, online softmax.
// G (banded) and P are PER-WAVE private (lgkmcnt only, no barrier).
// 2 barriers per key tile; next tile's k/v/kp prefetched into regs (T14).
// LDS ~106KB -> 1 block/CU (8 waves).
// ---------------------------------------------------------------------------
__global__ __launch_bounds__(512, 2) void attn_mfma(
    const u16* __restrict__ qa_g, const u16* __restrict__ qb_g,
    const u16* __restrict__ k_g, const u16* __restrict__ v_g,
    const u16* __restrict__ kp_g, u16* __restrict__ ctx) {
  __shared__ u16 kT[64 * 72];      // k tile [j][s]
  __shared__ u16 vT[64 * 72];      // v transposed [s][j]
  __shared__ u16 kpl[192 * 72];    // kp window [d][s]
  __shared__ float G[8][16 * 81];  // per-wave banded scores (stride 81)
  __shared__ u16 P[8][16 * 72];    // per-wave P tile [r][j]

  const int tid = threadIdx.x;
  const int w = tid >> 6, l = tid & 63;
  const int lg = l >> 4, lc = l & 15;
  const int bh = blockIdx.x;
  const int h = bh & 15;
  const int i0 = (7 - (int)blockIdx.y) * 128;   // longest blocks first
  const size_t bhOff = (size_t)bh << 16;
  const size_t hOff = (size_t)h * 2047 * 64;

  // persistent A-fragments: qa/qb rows i0 + w*16 + lc
  bf16x8 qaf[2], qbf[2];
#pragma unroll
  for (int ks = 0; ks < 2; ++ks) {
    size_t o = bhOff + (size_t)(i0 + w * 16 + lc) * 64 + ks * 32 + lg * 8;
    qaf[ks] = *reinterpret_cast<const bf16x8*>(&qa_g[o]);
    qbf[ks] = *reinterpret_cast<const bf16x8*>(&qb_g[o]);
  }

  // prefetch tile 0 into regs
  const int k_j = tid >> 3, k_c8 = (tid & 7) * 8;   // k/kp chunk coords
  const int v_j = tid & 63, v_s0 = (tid >> 6) * 8;  // v transpose coords
  u16x8 pk, pv, pp[3];
  {
    pk = *reinterpret_cast<const u16x8*>(&k_g[bhOff + (size_t)k_j * 64 + k_c8]);
    pv = *reinterpret_cast<const u16x8*>(&v_g[bhOff + (size_t)v_j * 64 + v_s0]);
#pragma unroll
    for (int r = 0; r < 3; ++r) {
      int idx = tid + r * 512;
      int d = idx >> 3, c8 = (idx & 7) * 8;
      int p = i0 + d; if (p > 2046) p = 2046;
      pp[r] = *reinterpret_cast<const u16x8*>(&kp_g[hOff + (size_t)p * 64 + c8]);
    }
  }

  f32x4 O[4];
  float m_r[4], l_r[4];
#pragma unroll
  for (int fj = 0; fj < 4; ++fj) O[fj] = (f32x4){0.f, 0.f, 0.f, 0.f};
#pragma unroll
  for (int reg = 0; reg < 4; ++reg) { m_r[reg] = NEG_INF_F; l_r[reg] = 0.f; }

  const int nt = (i0 >> 6) + 2;
  for (int jt = 0; jt < nt; ++jt) {
    const int j0 = jt * 64;
    __syncthreads();   // previous tile's LDS reads complete
    // write staged regs to LDS
    *reinterpret_cast<u16x8*>(&kT[k_j * 72 + k_c8]) = pk;
#pragma unroll
    for (int i2 = 0; i2 < 8; ++i2) vT[(v_s0 + i2) * 72 + v_j] = pv[i2];
#pragma unroll
    for (int r = 0; r < 3; ++r) {
      int idx = tid + r * 512;
      int d = idx >> 3, c8 = (idx & 7) * 8;
      *reinterpret_cast<u16x8*>(&kpl[d * 72 + c8]) = pp[r];
    }
    __syncthreads();
    // prefetch next tile (latency hides under compute below)
    if (jt + 1 < nt) {
      const int jn = j0 + 64, pbn = i0 + jn;
      pk = *reinterpret_cast<const u16x8*>(
          &k_g[bhOff + (size_t)(jn + k_j) * 64 + k_c8]);
      pv = *reinterpret_cast<const u16x8*>(
          &v_g[bhOff + (size_t)(jn + v_j) * 64 + v_s0]);
#pragma unroll
      for (int r = 0; r < 3; ++r) {
        int idx = tid + r * 512;
        int d = idx >> 3, c8 = (idx & 7) * 8;
        int p = pbn + d; if (p > 2046) p = 2046;
        pp[r] = *reinterpret_cast<const u16x8*>(&kp_g[hOff + (size_t)p * 64 + c8]);
      }
    }
    // fully-masked waves skip compute (still hit barriers next iter)
    if (j0 > i0 + w * 16 + 15) continue;

    f32x4 S[4], Gf[5];
#pragma unroll
    for (int fj = 0; fj < 4; ++fj) S[fj] = (f32x4){0.f, 0.f, 0.f, 0.f};
#pragma unroll
    for (int fg = 0; fg < 5; ++fg) Gf[fg] = (f32x4){0.f, 0.f, 0.f, 0.f};
#pragma unroll
    for (int ks = 0; ks < 2; ++ks) {
#pragma unroll
      for (int fj = 0; fj < 4; ++fj) {
        bf16x8 kf = *reinterpret_cast<const bf16x8*>(
            &kT[(fj * 16 + lc) * 72 + ks * 32 + lg * 8]);
        S[fj] = __builtin_amdgcn_mfma_f32_16x16x32_bf16(qaf[ks], kf, S[fj], 0, 0, 0);
      }
#pragma unroll
      for (int fg = 0; fg < 5; ++fg) {
        bf16x8 pf = *reinterpret_cast<const bf16x8*>(
            &kpl[((w + fg) * 16 + lc) * 72 + ks * 32 + lg * 8]);
        Gf[fg] = __builtin_amdgcn_mfma_f32_16x16x32_bf16(qbf[ks], pf, Gf[fg], 0, 0, 0);
      }
    }
    // per-wave G spill (stride 81 -> <=2-way banks)
    float* Gw = G[w];
#pragma unroll
    for (int fg = 0; fg < 5; ++fg)
#pragma unroll
      for (int reg = 0; reg < 4; ++reg)
        Gw[(lg * 4 + reg) * 81 + fg * 16 + lc] = Gf[fg][reg];
    asm volatile("s_waitcnt lgkmcnt(0)" ::: "memory");
    __builtin_amdgcn_sched_barrier(0);
    // skew gather + causal mask
    const bool needMask = (j0 + 63 > i0 + w * 16);
#pragma unroll
    for (int fj = 0; fj < 4; ++fj)
#pragma unroll
      for (int reg = 0; reg < 4; ++reg) {
        int rf = lg * 4 + reg;
        float sv = S[fj][reg] + Gw[rf * 81 + rf + fj * 16 + lc];
        if (needMask && (i0 + w * 16 + rf) < (j0 + fj * 16 + lc)) sv = NEG_INF_F;
        S[fj][reg] = sv;
      }
    // online softmax (16-lane row groups)
#pragma unroll
    for (int reg = 0; reg < 4; ++reg) {
      float mx = fmaxf(fmaxf(S[0][reg], S[1][reg]), fmaxf(S[2][reg], S[3][reg]));
      mx = fmaxf(mx, __shfl_xor(mx, 1));
      mx = fmaxf(mx, __shfl_xor(mx, 2));
      mx = fmaxf(mx, __shfl_xor(mx, 4));
      mx = fmaxf(mx, __shfl_xor(mx, 8));
      float mnew = fmaxf(m_r[reg], mx);
      float corr = __expf(m_r[reg] - mnew);
      float rs = 0.f;
#pragma unroll
      for (int fj = 0; fj < 4; ++fj) {
        float p = __expf(S[fj][reg] - mnew);
        S[fj][reg] = p;
        rs += p;
      }
      rs += __shfl_xor(rs, 1); rs += __shfl_xor(rs, 2);
      rs += __shfl_xor(rs, 4); rs += __shfl_xor(rs, 8);
      l_r[reg] = l_r[reg] * corr + rs;
      m_r[reg] = mnew;
#pragma unroll
      for (int fj = 0; fj < 4; ++fj) O[fj][reg] *= corr;
    }
    // per-wave P spill (no barrier needed)
    u16* Pw = P[w];
#pragma unroll
    for (int fj = 0; fj < 4; ++fj)
#pragma unroll
      for (int reg = 0; reg < 4; ++reg)
        Pw[(lg * 4 + reg) * 72 + fj * 16 + lc] = f2bf(S[fj][reg]);
    asm volatile("s_waitcnt lgkmcnt(0)" ::: "memory");
    __builtin_amdgcn_sched_barrier(0);
    // PV: O += P @ V
#pragma unroll
    for (int ks = 0; ks < 2; ++ks) {
      bf16x8 pa = *reinterpret_cast<const bf16x8*>(&Pw[lc * 72 + ks * 32 + lg * 8]);
#pragma unroll
      for (int fj = 0; fj < 4; ++fj) {
        bf16x8 vb = *reinterpret_cast<const bf16x8*>(
            &vT[(fj * 16 + lc) * 72 + ks * 32 + lg * 8]);
        O[fj] = __builtin_amdgcn_mfma_f32_16x16x32_bf16(pa, vb, O[fj], 0, 0, 0);
      }
    }
  }

  // normalize + write ctx (b, t, e) as bf16
  const int b = bh >> 4;
#pragma unroll
  for (int reg = 0; reg < 4; ++reg) {
    float inv = 1.f / l_r[reg];
    int r = w * 16 + lg * 4 + reg;
#pragma unroll
    for (int fj = 0; fj < 4; ++fj)
      ctx[((size_t)b * 1024 + i0 + r) * 1024 + h * 64 + fj * 16 + lc] =
          f2bf(O[fj][reg] * inv);
  }
}

// ---------------------------------------------------------------------------
extern "C" void kernel_launch(void* const* d_in, const int* in_sizes, int n_in,
                              void* d_out, int out_size, void* d_ws, size_t ws_size,
                              hipStream_t stream) {
  const float* x       = (const float*)d_in[0];
  const float* Wq      = (const float*)d_in[1];
  const float* Wk      = (const float*)d_in[2];
  const float* Wkp     = (const float*)d_in[3];
  const float* Wv      = (const float*)d_in[4];
  const float* Wu      = (const float*)d_in[5];
  const float* bu      = (const float*)d_in[6];
  const float* parma   = (const float*)d_in[7];   // flat (h*s) = 1024
  const float* parmb   = (const float*)d_in[8];
  const float* pos_emb = (const float*)d_in[9];   // (2047, 1024)
  float* out = (float*)d_out;

  // workspace (u16 elements); wqT/wkT/wvT contiguous => fused QKV B-matrix
  u16* W = (u16*)d_ws;
  u16* x_bf   = W;                      // 4194304
  u16* pos_bf = x_bf + 4194304;         // 2096128
  u16* wqT    = pos_bf + 2096128;       // 1048576 each
  u16* wkT    = wqT + 1048576;
  u16* wvT    = wkT + 1048576;
  u16* wkpT   = wvT + 1048576;
  u16* wuT    = wkpT + 1048576;
  u16* qa     = wuT + 1048576;          // 4194304 (b,h,t,s)
  u16* qb     = qa + 4194304;
  u16* kb     = qb + 4194304;
  u16* vb     = kb + 4194304;
  u16* kp     = vb + 4194304;           // 2096128 (h,p,s)
  u16* ctx    = kp + 2096128;           // 4194304 (b,t,e)

  // conversions
  cvt_bf16<<<4096, 256, 0, stream>>>(x, x_bf, 1048576);
  cvt_bf16<<<2047, 256, 0, stream>>>(pos_emb, pos_bf, 524032);
  cvt_w_tr<<<dim3(16, 16, 5), 256, 0, stream>>>(Wq, Wk, Wkp, Wv, Wu,
                                                wqT, wkT, wkpT, wvT, wuT);
  // fused QKV + KP projections
  gemm_qkvp<<<dim3(32, 32), 512, 0, stream>>>(x_bf, pos_bf, wqT, wkpT,
                                              qa, qb, kb, vb, kp, parma, parmb);
  // attention
  attn_mfma<<<dim3(64, 8), 512, 0, stream>>>(qa, qb, kb, vb, kp, ctx);
  // out = ctx @ Wu + bu
  gemm_out<<<dim3(8, 32), 512, 0, stream>>>(ctx, wuT, out, bu);
}

// Round 8
// 250.216 us; speedup vs baseline: 7.0783x; 1.0102x over previous
//
#include <hip/hip_runtime.h>

typedef unsigned short u16;
typedef unsigned int   u32;
using bf16x8 = __attribute__((ext_vector_type(8))) __bf16;
using f32x4  = __attribute__((ext_vector_type(4))) float;
using u16x8  = __attribute__((ext_vector_type(8))) u16;

#define NEG_INF_F (-1e30f)

__device__ __forceinline__ u16 f2bf(float f) {
  u32 u = __float_as_uint(f);
  u32 r = (u + 0x7FFFu + ((u >> 16) & 1u)) >> 16;   // RNE
  return (u16)r;
}

__device__ __forceinline__ void async_copy16(const void* g, void* lds) {
  __builtin_amdgcn_global_load_lds(
      (const __attribute__((address_space(1))) void*)g,
      (__attribute__((address_space(3))) void*)lds, 16, 0, 0);
}

// ---------------------------------------------------------------------------
// fp32 -> bf16 row-major, 4 elems/thread
// ---------------------------------------------------------------------------
__global__ __launch_bounds__(256) void cvt_bf16(const float* __restrict__ in,
                                                u16* __restrict__ out, int n4) {
  int i = blockIdx.x * 256 + threadIdx.x;
  if (i >= n4) return;
  float4 v = reinterpret_cast<const float4*>(in)[i];
  u16 o0 = f2bf(v.x), o1 = f2bf(v.y), o2 = f2bf(v.z), o3 = f2bf(v.w);
  ushort4 o = {o0, o1, o2, o3};
  reinterpret_cast<ushort4*>(out)[i] = o;
}

// ---------------------------------------------------------------------------
// fp32 W[1024][1024] -> bf16 W^T[1024][1024], 5 weights via blockIdx.z
// ---------------------------------------------------------------------------
__global__ __launch_bounds__(256) void cvt_w_tr(
    const float* __restrict__ w0, const float* __restrict__ w1,
    const float* __restrict__ w2, const float* __restrict__ w3,
    const float* __restrict__ w4,
    u16* __restrict__ o0, u16* __restrict__ o1, u16* __restrict__ o2,
    u16* __restrict__ o3, u16* __restrict__ o4) {
  __shared__ float tile[64][65];
  const float* src; u16* dst;
  switch (blockIdx.z) {
    case 0: src = w0; dst = o0; break;
    case 1: src = w1; dst = o1; break;
    case 2: src = w2; dst = o2; break;
    case 3: src = w3; dst = o3; break;
    default: src = w4; dst = o4; break;
  }
  const int tid = threadIdx.x;
  const int r0 = blockIdx.y * 64;   // k-tile
  const int c0 = blockIdx.x * 64;   // n-tile
#pragma unroll
  for (int i = 0; i < 16; ++i) {
    int lin = tid + i * 256;
    int r = lin >> 6, c = lin & 63;
    tile[r][c] = src[(size_t)(r0 + r) * 1024 + c0 + c];
  }
  __syncthreads();
#pragma unroll
  for (int i = 0; i < 16; ++i) {
    int lin = tid + i * 256;
    int n = lin >> 6, k = lin & 63;
    dst[(size_t)(c0 + n) * 1024 + r0 + k] = f2bf(tile[k][n]);
  }
}

// ---------------------------------------------------------------------------
// Fused QKV + KP projection GEMM, 256x256 tile / BK=64 / 8 waves (2Mx4N).
// grid = 224 blocks: [0,192) QKV (16 M-tiles x 12 N-tiles over [Wq|Wk|Wv]),
// [192,224) KP (8 M-tiles x 4 N-tiles over Wkp, M=2047).
// T3/T4: stage(t+1) issued BEFORE compute(t), counted s_waitcnt vmcnt(8),
// raw s_barrier (no compiler vmcnt(0) drain). T2: LDS chunk swizzle
// cc ^= (row&7) applied on BOTH sides (pre-swizzled global source address +
// swizzled ds_read chunk) -- global_load_lds dest stays linear (rule #21).
// LDS 128KB -> 1 block/CU. Epilogues scatter bf16 to (b,h,t,s) / (h,p,s).
// ---------------------------------------------------------------------------
__device__ __forceinline__ void stage_tile(const u16* __restrict__ gsrc,
                                           int row0, int kbk, int maxRow,
                                           u16* lds, int tid) {
  const int lane = tid & 63;
  const int wchunk = (tid >> 6) * 64;          // wave-uniform chunk base
#pragma unroll
  for (int r4 = 0; r4 < 4; ++r4) {
    int cbase = wchunk + r4 * 512;             // wave-uniform
    int c = cbase + lane;                      // chunk 0..2047 (16B each)
    int row = c >> 3, cc = c & 7;
    int scc = cc ^ (row & 7);                  // pre-swizzled source chunk
    int gr = row0 + row; if (gr > maxRow) gr = maxRow;
    async_copy16(&gsrc[(size_t)gr * 1024 + kbk + scc * 8],
                 lds + (size_t)cbase * 8);     // uniform base; HW adds lane*16
  }
}

__global__ __launch_bounds__(512, 2) void gemm_qkvp(
    const u16* __restrict__ x_bf, const u16* __restrict__ pos_bf,
    const u16* __restrict__ BtQKV, const u16* __restrict__ BtKP,
    u16* __restrict__ qa, u16* __restrict__ qb, u16* __restrict__ kb,
    u16* __restrict__ vb, u16* __restrict__ kp,
    const float* __restrict__ parma, const float* __restrict__ parmb) {
  __shared__ __align__(16) u16 As[2][256 * 64];
  __shared__ __align__(16) u16 Bs[2][256 * 64];

  const int tid = threadIdx.x;
  const int w = tid >> 6, l = tid & 63;
  const int lg = l >> 4, lc = l & 15;
  const int wr = w >> 2, wc = w & 3;           // 2x4 wave grid; wave = 128x64
  const int bid = blockIdx.x;
  const bool isKP = bid >= 192;
  int row0, col0;
  const u16 *A, *Bt;
  int maxRowA, maxRowB;
  if (!isKP) {
    int by = bid / 12, bx = bid - by * 12;
    row0 = by * 256; col0 = bx * 256;
    A = x_bf; Bt = BtQKV; maxRowA = 4095; maxRowB = 3071;
  } else {
    int idx = bid - 192;
    int by = idx >> 2, bx = idx & 3;
    row0 = by * 256; col0 = bx * 256;
    A = pos_bf; Bt = BtKP; maxRowA = 2046; maxRowB = 1023;
  }

  f32x4 acc[8][4];
#pragma unroll
  for (int fi = 0; fi < 8; ++fi)
#pragma unroll
    for (int fj = 0; fj < 4; ++fj) acc[fi][fj] = (f32x4){0.f, 0.f, 0.f, 0.f};

  // prologue: stage tile 0
  stage_tile(A, row0, 0, maxRowA, &As[0][0], tid);
  stage_tile(Bt, col0, 0, maxRowB, &Bs[0][0], tid);

  const int NT = 16;
  for (int t = 0; t < NT; ++t) {
    const int cur = t & 1;
    if (t + 1 < NT) {
      // issue next tile (8 loads/thread) BEFORE waiting on current
      stage_tile(A, row0, (t + 1) * 64, maxRowA, &As[cur ^ 1][0], tid);
      stage_tile(Bt, col0, (t + 1) * 64, maxRowB, &Bs[cur ^ 1][0], tid);
      asm volatile("s_waitcnt vmcnt(8)" ::: "memory");   // tile t landed
    } else {
      asm volatile("s_waitcnt vmcnt(0)" ::: "memory");
    }
    __builtin_amdgcn_s_barrier();            // all waves' tile-t loads visible
    __builtin_amdgcn_sched_barrier(0);

    const u16* bufA = &As[cur][0];
    const u16* bufB = &Bs[cur][0];
#pragma unroll
    for (int ks = 0; ks < 2; ++ks) {
      const int pc = ((ks << 2) | lg) ^ (lc & 7);        // swizzled read chunk
      const u16* pA = bufA + (wr * 128 + lc) * 64 + pc * 8;
      const u16* pB = bufB + (wc * 64 + lc) * 64 + pc * 8;
      bf16x8 af[8], bfr[4];
#pragma unroll
      for (int fi = 0; fi < 8; ++fi)
        af[fi] = *reinterpret_cast<const bf16x8*>(pA + fi * 1024);
#pragma unroll
      for (int fj = 0; fj < 4; ++fj)
        bfr[fj] = *reinterpret_cast<const bf16x8*>(pB + fj * 1024);
#pragma unroll
      for (int fi = 0; fi < 8; ++fi)
#pragma unroll
        for (int fj = 0; fj < 4; ++fj)
          acc[fi][fj] = __builtin_amdgcn_mfma_f32_16x16x32_bf16(
              af[fi], bfr[fj], acc[fi][fj], 0, 0, 0);
    }
    __builtin_amdgcn_s_barrier();            // reads done before overwrite
  }

#pragma unroll
  for (int fi = 0; fi < 8; ++fi)
#pragma unroll
    for (int fj = 0; fj < 4; ++fj)
#pragma unroll
      for (int reg = 0; reg < 4; ++reg) {
        int R = row0 + wr * 128 + fi * 16 + lg * 4 + reg;
        int C = col0 + wc * 64 + fj * 16 + lc;
        float val = acc[fi][fj][reg];
        if (isKP) {
          if (R < 2047) {
            int hh = C >> 6, ss = C & 63;
            kp[((size_t)hh * 2047 + R) * 64 + ss] = f2bf(val);
          }
        } else {
          int wsel = C >> 10, Cl = C & 1023;
          int bi = R >> 10, tt = R & 1023, hh = Cl >> 6, ss = Cl & 63;
          size_t o = ((size_t)(bi * 16 + hh) << 16) + (size_t)tt * 64 + ss;
          if (wsel == 0) {
            qa[o] = f2bf(val + parma[Cl]);
            qb[o] = f2bf(val + parmb[Cl]);
          } else if (wsel == 1) {
            kb[o] = f2bf(val);
          } else {
            vb[o] = f2bf(val);
          }
        }
      }
}

// ---------------------------------------------------------------------------
// Output projection: out(4096x1024 fp32) = ctx @ Wu + bu. (unchanged)
// ---------------------------------------------------------------------------
__global__ __launch_bounds__(512, 2) void gemm_out(
    const u16* __restrict__ A, const u16* __restrict__ Bt,
    float* __restrict__ outF, const float* __restrict__ bias) {
  __shared__ u16 As[128 * 64];
  __shared__ u16 Bs[128 * 64];
  const int tid = threadIdx.x;
  const int w = tid >> 6, l = tid & 63;
  const int lg = l >> 4, lc = l & 15;
  const int wr = w >> 2, wc = w & 3;
  const int row0 = blockIdx.y * 128;
  const int col0 = blockIdx.x * 128;

  f32x4 acc[4][2];
#pragma unroll
  for (int fi = 0; fi < 4; ++fi)
#pragma unroll
    for (int fj = 0; fj < 2; ++fj) acc[fi][fj] = (f32x4){0.f, 0.f, 0.f, 0.f};

  for (int kbk = 0; kbk < 1024; kbk += 64) {
#pragma unroll
    for (int it2 = 0; it2 < 2; ++it2) {
      int seg = w * 2 + it2;
      int r = seg * 8 + (l >> 3);
      int c8 = (l & 7) * 8;
      async_copy16(&A[(size_t)(row0 + r) * 1024 + kbk + c8], &As[seg * 512]);
      async_copy16(&Bt[(size_t)(col0 + r) * 1024 + kbk + c8], &Bs[seg * 512]);
    }
    __syncthreads();
#pragma unroll
    for (int ks = 0; ks < 2; ++ks) {
      bf16x8 af[4], bfr[2];
#pragma unroll
      for (int fi = 0; fi < 4; ++fi)
        af[fi] = *reinterpret_cast<const bf16x8*>(
            &As[(wr * 64 + fi * 16 + lc) * 64 + ks * 32 + lg * 8]);
#pragma unroll
      for (int fj = 0; fj < 2; ++fj)
        bfr[fj] = *reinterpret_cast<const bf16x8*>(
            &Bs[(wc * 32 + fj * 16 + lc) * 64 + ks * 32 + lg * 8]);
#pragma unroll
      for (int fi = 0; fi < 4; ++fi)
#pragma unroll
        for (int fj = 0; fj < 2; ++fj)
          acc[fi][fj] = __builtin_amdgcn_mfma_f32_16x16x32_bf16(
              af[fi], bfr[fj], acc[fi][fj], 0, 0, 0);
    }
    __syncthreads();
  }

#pragma unroll
  for (int fi = 0; fi < 4; ++fi)
#pragma unroll
    for (int fj = 0; fj < 2; ++fj)
#pragma unroll
      for (int reg = 0; reg < 4; ++reg) {
        int R = row0 + wr * 64 + fi * 16 + lg * 4 + reg;
        int C = col0 + wc * 32 + fj * 16 + lc;
        outF[(size_t)R * 1024 + C] = acc[fi][fj][reg] + bias[C];
      }
}

// ---------------------------------------------------------------------------
// MFMA flash attention, QBLK=128 / 8 waves / KBLK=64. (unchanged)
// ---------------------------------------------------------------------------
__global__ __launch_bounds__(512, 2) void attn_mfma(
    const u16* __restrict__ qa_g, const u16* __restrict__ qb_g,
    const u16* __restrict__ k_g, const u16* __restrict__ v_g,
    const u16* __restrict__ kp_g, u16* __restrict__ ctx) {
  __shared__ u16 kT[64 * 72];      // k tile [j][s]
  __shared__ u16 vT[64 * 72];      // v transposed [s][j]
  __shared__ u16 kpl[192 * 72];    // kp window [d][s]
  __shared__ float G[8][16 * 81];  // per-wave banded scores (stride 81)
  __shared__ u16 P[8][16 * 72];    // per-wave P tile [r][j]

  const int tid = threadIdx.x;
  const int w = tid >> 6, l = tid & 63;
  const int lg = l >> 4, lc = l & 15;
  const int bh = blockIdx.x;
  const int h = bh & 15;
  const int i0 = (7 - (int)blockIdx.y) * 128;   // longest blocks first
  const size_t bhOff = (size_t)bh << 16;
  const size_t hOff = (size_t)h * 2047 * 64;

  // persistent A-fragments: qa/qb rows i0 + w*16 + lc
  bf16x8 qaf[2], qbf[2];
#pragma unroll
  for (int ks = 0; ks < 2; ++ks) {
    size_t o = bhOff + (size_t)(i0 + w * 16 + lc) * 64 + ks * 32 + lg * 8;
    qaf[ks] = *reinterpret_cast<const bf16x8*>(&qa_g[o]);
    qbf[ks] = *reinterpret_cast<const bf16x8*>(&qb_g[o]);
  }

  // prefetch tile 0 into regs
  const int k_j = tid >> 3, k_c8 = (tid & 7) * 8;   // k/kp chunk coords
  const int v_j = tid & 63, v_s0 = (tid >> 6) * 8;  // v transpose coords
  u16x8 pk, pv, pp[3];
  {
    pk = *reinterpret_cast<const u16x8*>(&k_g[bhOff + (size_t)k_j * 64 + k_c8]);
    pv = *reinterpret_cast<const u16x8*>(&v_g[bhOff + (size_t)v_j * 64 + v_s0]);
#pragma unroll
    for (int r = 0; r < 3; ++r) {
      int idx = tid + r * 512;
      int d = idx >> 3, c8 = (idx & 7) * 8;
      int p = i0 + d; if (p > 2046) p = 2046;
      pp[r] = *reinterpret_cast<const u16x8*>(&kp_g[hOff + (size_t)p * 64 + c8]);
    }
  }

  f32x4 O[4];
  float m_r[4], l_r[4];
#pragma unroll
  for (int fj = 0; fj < 4; ++fj) O[fj] = (f32x4){0.f, 0.f, 0.f, 0.f};
#pragma unroll
  for (int reg = 0; reg < 4; ++reg) { m_r[reg] = NEG_INF_F; l_r[reg] = 0.f; }

  const int nt = (i0 >> 6) + 2;
  for (int jt = 0; jt < nt; ++jt) {
    const int j0 = jt * 64;
    __syncthreads();   // previous tile's LDS reads complete
    // write staged regs to LDS
    *reinterpret_cast<u16x8*>(&kT[k_j * 72 + k_c8]) = pk;
#pragma unroll
    for (int i2 = 0; i2 < 8; ++i2) vT[(v_s0 + i2) * 72 + v_j] = pv[i2];
#pragma unroll
    for (int r = 0; r < 3; ++r) {
      int idx = tid + r * 512;
      int d = idx >> 3, c8 = (idx & 7) * 8;
      *reinterpret_cast<u16x8*>(&kpl[d * 72 + c8]) = pp[r];
    }
    __syncthreads();
    // prefetch next tile (latency hides under compute below)
    if (jt + 1 < nt) {
      const int jn = j0 + 64, pbn = i0 + jn;
      pk = *reinterpret_cast<const u16x8*>(
          &k_g[bhOff + (size_t)(jn + k_j) * 64 + k_c8]);
      pv = *reinterpret_cast<const u16x8*>(
          &v_g[bhOff + (size_t)(jn + v_j) * 64 + v_s0]);
#pragma unroll
      for (int r = 0; r < 3; ++r) {
        int idx = tid + r * 512;
        int d = idx >> 3, c8 = (idx & 7) * 8;
        int p = pbn + d; if (p > 2046) p = 2046;
        pp[r] = *reinterpret_cast<const u16x8*>(&kp_g[hOff + (size_t)p * 64 + c8]);
      }
    }
    // fully-masked waves skip compute (still hit barriers next iter)
    if (j0 > i0 + w * 16 + 15) continue;

    f32x4 S[4], Gf[5];
#pragma unroll
    for (int fj = 0; fj < 4; ++fj) S[fj] = (f32x4){0.f, 0.f, 0.f, 0.f};
#pragma unroll
    for (int fg = 0; fg < 5; ++fg) Gf[fg] = (f32x4){0.f, 0.f, 0.f, 0.f};
#pragma unroll
    for (int ks = 0; ks < 2; ++ks) {
#pragma unroll
      for (int fj = 0; fj < 4; ++fj) {
        bf16x8 kf = *reinterpret_cast<const bf16x8*>(
            &kT[(fj * 16 + lc) * 72 + ks * 32 + lg * 8]);
        S[fj] = __builtin_amdgcn_mfma_f32_16x16x32_bf16(qaf[ks], kf, S[fj], 0, 0, 0);
      }
#pragma unroll
      for (int fg = 0; fg < 5; ++fg) {
        bf16x8 pf = *reinterpret_cast<const bf16x8*>(
            &kpl[((w + fg) * 16 + lc) * 72 + ks * 32 + lg * 8]);
        Gf[fg] = __builtin_amdgcn_mfma_f32_16x16x32_bf16(qbf[ks], pf, Gf[fg], 0, 0, 0);
      }
    }
    // per-wave G spill (stride 81 -> <=2-way banks)
    float* Gw = G[w];
#pragma unroll
    for (int fg = 0; fg < 5; ++fg)
#pragma unroll
      for (int reg = 0; reg < 4; ++reg)
        Gw[(lg * 4 + reg) * 81 + fg * 16 + lc] = Gf[fg][reg];
    asm volatile("s_waitcnt lgkmcnt(0)" ::: "memory");
    __builtin_amdgcn_sched_barrier(0);
    // skew gather + causal mask
    const bool needMask = (j0 + 63 > i0 + w * 16);
#pragma unroll
    for (int fj = 0; fj < 4; ++fj)
#pragma unroll
      for (int reg = 0; reg < 4; ++reg) {
        int rf = lg * 4 + reg;
        float sv = S[fj][reg] + Gw[rf * 81 + rf + fj * 16 + lc];
        if (needMask && (i0 + w * 16 + rf) < (j0 + fj * 16 + lc)) sv = NEG_INF_F;
        S[fj][reg] = sv;
      }
    // online softmax (16-lane row groups)
#pragma unroll
    for (int reg = 0; reg < 4; ++reg) {
      float mx = fmaxf(fmaxf(S[0][reg], S[1][reg]), fmaxf(S[2][reg], S[3][reg]));
      mx = fmaxf(mx, __shfl_xor(mx, 1));
      mx = fmaxf(mx, __shfl_xor(mx, 2));
      mx = fmaxf(mx, __shfl_xor(mx, 4));
      mx = fmaxf(mx, __shfl_xor(mx, 8));
      float mnew = fmaxf(m_r[reg], mx);
      float corr = __expf(m_r[reg] - mnew);
      float rs = 0.f;
#pragma unroll
      for (int fj = 0; fj < 4; ++fj) {
        float p = __expf(S[fj][reg] - mnew);
        S[fj][reg] = p;
        rs += p;
      }
      rs += __shfl_xor(rs, 1); rs += __shfl_xor(rs, 2);
      rs += __shfl_xor(rs, 4); rs += __shfl_xor(rs, 8);
      l_r[reg] = l_r[reg] * corr + rs;
      m_r[reg] = mnew;
#pragma unroll
      for (int fj = 0; fj < 4; ++fj) O[fj][reg] *= corr;
    }
    // per-wave P spill (no barrier needed)
    u16* Pw = P[w];
#pragma unroll
    for (int fj = 0; fj < 4; ++fj)
#pragma unroll
      for (int reg = 0; reg < 4; ++reg)
        Pw[(lg * 4 + reg) * 72 + fj * 16 + lc] = f2bf(S[fj][reg]);
    asm volatile("s_waitcnt lgkmcnt(0)" ::: "memory");
    __builtin_amdgcn_sched_barrier(0);
    // PV: O += P @ V
#pragma unroll
    for (int ks = 0; ks < 2; ++ks) {
      bf16x8 pa = *reinterpret_cast<const bf16x8*>(&Pw[lc * 72 + ks * 32 + lg * 8]);
#pragma unroll
      for (int fj = 0; fj < 4; ++fj) {
        bf16x8 vb = *reinterpret_cast<const bf16x8*>(
            &vT[(fj * 16 + lc) * 72 + ks * 32 + lg * 8]);
        O[fj] = __builtin_amdgcn_mfma_f32_16x16x32_bf16(pa, vb, O[fj], 0, 0, 0);
      }
    }
  }

  // normalize + write ctx (b, t, e) as bf16
  const int b = bh >> 4;
#pragma unroll
  for (int reg = 0; reg < 4; ++reg) {
    float inv = 1.f / l_r[reg];
    int r = w * 16 + lg * 4 + reg;
#pragma unroll
    for (int fj = 0; fj < 4; ++fj)
      ctx[((size_t)b * 1024 + i0 + r) * 1024 + h * 64 + fj * 16 + lc] =
          f2bf(O[fj][reg] * inv);
  }
}

// ---------------------------------------------------------------------------
extern "C" void kernel_launch(void* const* d_in, const int* in_sizes, int n_in,
                              void* d_out, int out_size, void* d_ws, size_t ws_size,
                              hipStream_t stream) {
  const float* x       = (const float*)d_in[0];
  const float* Wq      = (const float*)d_in[1];
  const float* Wk      = (const float*)d_in[2];
  const float* Wkp     = (const float*)d_in[3];
  const float* Wv      = (const float*)d_in[4];
  const float* Wu      = (const float*)d_in[5];
  const float* bu      = (const float*)d_in[6];
  const float* parma   = (const float*)d_in[7];   // flat (h*s) = 1024
  const float* parmb   = (const float*)d_in[8];
  const float* pos_emb = (const float*)d_in[9];   // (2047, 1024)
  float* out = (float*)d_out;

  // workspace (u16 elements); wqT/wkT/wvT contiguous => fused QKV B-matrix
  u16* W = (u16*)d_ws;
  u16* x_bf   = W;                      // 4194304
  u16* pos_bf = x_bf + 4194304;         // 2096128
  u16* wqT    = pos_bf + 2096128;       // 1048576 each
  u16* wkT    = wqT + 1048576;
  u16* wvT    = wkT + 1048576;
  u16* wkpT   = wvT + 1048576;
  u16* wuT    = wkpT + 1048576;
  u16* qa     = wuT + 1048576;          // 4194304 (b,h,t,s)
  u16* qb     = qa + 4194304;
  u16* kb     = qb + 4194304;
  u16* vb     = kb + 4194304;
  u16* kp     = vb + 4194304;           // 2096128 (h,p,s)
  u16* ctx    = kp + 2096128;           // 4194304 (b,t,e)

  // conversions
  cvt_bf16<<<4096, 256, 0, stream>>>(x, x_bf, 1048576);
  cvt_bf16<<<2047, 256, 0, stream>>>(pos_emb, pos_bf, 524032);
  cvt_w_tr<<<dim3(16, 16, 5), 256, 0, stream>>>(Wq, Wk, Wkp, Wv, Wu,
                                                wqT, wkT, wkpT, wvT, wuT);
  // fused QKV + KP projections (256^2 tiles, 224 blocks, 1/CU)
  gemm_qkvp<<<224, 512, 0, stream>>>(x_bf, pos_bf, wqT, wkpT,
                                     qa, qb, kb, vb, kp, parma, parmb);
  // attention
  attn_mfma<<<dim3(64, 8), 512, 0, stream>>>(qa, qb, kb, vb, kp, ctx);
  // out = ctx @ Wu + bu
  gemm_out<<<dim3(8, 32), 512, 0, stream>>>(ctx, wuT, out, bu);
}

// Round 10
// 248.590 us; speedup vs baseline: 7.1246x; 1.0065x over previous
//
#include <hip/hip_runtime.h>

typedef unsigned short u16;
typedef unsigned int   u32;
using bf16x8 = __attribute__((ext_vector_type(8))) __bf16;
using f32x4  = __attribute__((ext_vector_type(4))) float;
using u16x8  = __attribute__((ext_vector_type(8))) u16;

#define NEG_INF_F (-1e30f)

__device__ __forceinline__ u16 f2bf(float f) {
  u32 u = __float_as_uint(f);
  u32 r = (u + 0x7FFFu + ((u >> 16) & 1u)) >> 16;   // RNE
  return (u16)r;
}

__device__ __forceinline__ void async_copy16(const void* g, void* lds) {
  __builtin_amdgcn_global_load_lds(
      (const __attribute__((address_space(1))) void*)g,
      (__attribute__((address_space(3))) void*)lds, 16, 0, 0);
}

// ---------------------------------------------------------------------------
// fp32 -> bf16 row-major, 4 elems/thread
// ---------------------------------------------------------------------------
__global__ __launch_bounds__(256) void cvt_bf16(const float* __restrict__ in,
                                                u16* __restrict__ out, int n4) {
  int i = blockIdx.x * 256 + threadIdx.x;
  if (i >= n4) return;
  float4 v = reinterpret_cast<const float4*>(in)[i];
  u16 o0 = f2bf(v.x), o1 = f2bf(v.y), o2 = f2bf(v.z), o3 = f2bf(v.w);
  ushort4 o = {o0, o1, o2, o3};
  reinterpret_cast<ushort4*>(out)[i] = o;
}

// ---------------------------------------------------------------------------
// fp32 W[1024][1024] -> bf16 W^T[1024][1024], 5 weights via blockIdx.z
// ---------------------------------------------------------------------------
__global__ __launch_bounds__(256) void cvt_w_tr(
    const float* __restrict__ w0, const float* __restrict__ w1,
    const float* __restrict__ w2, const float* __restrict__ w3,
    const float* __restrict__ w4,
    u16* __restrict__ o0, u16* __restrict__ o1, u16* __restrict__ o2,
    u16* __restrict__ o3, u16* __restrict__ o4) {
  __shared__ float tile[64][65];
  const float* src; u16* dst;
  switch (blockIdx.z) {
    case 0: src = w0; dst = o0; break;
    case 1: src = w1; dst = o1; break;
    case 2: src = w2; dst = o2; break;
    case 3: src = w3; dst = o3; break;
    default: src = w4; dst = o4; break;
  }
  const int tid = threadIdx.x;
  const int r0 = blockIdx.y * 64;   // k-tile
  const int c0 = blockIdx.x * 64;   // n-tile
#pragma unroll
  for (int i = 0; i < 16; ++i) {
    int lin = tid + i * 256;
    int r = lin >> 6, c = lin & 63;
    tile[r][c] = src[(size_t)(r0 + r) * 1024 + c0 + c];
  }
  __syncthreads();
#pragma unroll
  for (int i = 0; i < 16; ++i) {
    int lin = tid + i * 256;
    int n = lin >> 6, k = lin & 63;
    dst[(size_t)(c0 + n) * 1024 + r0 + k] = f2bf(tile[k][n]);
  }
}

// ---------------------------------------------------------------------------
// Fused QKV + KP projection GEMM, 256x256 tile / BK=64 / 8 waves (2Mx4N).
// grid = 224 blocks: [0,192) QKV (16 M-tiles x 12 N-tiles over [Wq|Wk|Wv]),
// [192,224) KP (8 M-tiles x 4 N-tiles over Wkp, M=2047).
// T3-minimum schedule (catalog §5.5): stage(t+1) issued BEFORE compute(t);
// the single __syncthreads() at loop bottom drains vmcnt(0) exactly when
// tile t+1 is needed -> load latency hides under the 64-MFMA phase.
// T2: chunk swizzle cc ^= (row&7) on BOTH sides (pre-swizzled global source,
// swizzled ds_read chunk); global_load_lds dest stays linear (rule #21).
// LDS 128KB -> 1 block/CU. Epilogues scatter bf16 to (b,h,t,s) / (h,p,s).
// ---------------------------------------------------------------------------
__device__ __forceinline__ void stage_tile(const u16* __restrict__ gsrc,
                                           int row0, int kbk, int maxRow,
                                           u16* lds, int tid) {
  const int lane = tid & 63;
  const int wchunk = (tid >> 6) * 64;          // wave-uniform chunk base
#pragma unroll
  for (int r4 = 0; r4 < 4; ++r4) {
    int cbase = wchunk + r4 * 512;             // wave-uniform
    int c = cbase + lane;                      // chunk 0..2047 (16B each)
    int row = c >> 3, cc = c & 7;
    int scc = cc ^ (row & 7);                  // pre-swizzled source chunk
    int gr = row0 + row; if (gr > maxRow) gr = maxRow;
    async_copy16(&gsrc[(size_t)gr * 1024 + kbk + scc * 8],
                 lds + (size_t)cbase * 8);     // uniform base; HW adds lane*16
  }
}

__global__ __launch_bounds__(512, 2) void gemm_qkvp(
    const u16* __restrict__ x_bf, const u16* __restrict__ pos_bf,
    const u16* __restrict__ BtQKV, const u16* __restrict__ BtKP,
    u16* __restrict__ qa, u16* __restrict__ qb, u16* __restrict__ kb,
    u16* __restrict__ vb, u16* __restrict__ kp,
    const float* __restrict__ parma, const float* __restrict__ parmb) {
  __shared__ __align__(16) u16 As[2][256 * 64];
  __shared__ __align__(16) u16 Bs[2][256 * 64];

  const int tid = threadIdx.x;
  const int w = tid >> 6, l = tid & 63;
  const int lg = l >> 4, lc = l & 15;
  const int wr = w >> 2, wc = w & 3;           // 2x4 wave grid; wave = 128x64
  const int bid = blockIdx.x;
  const bool isKP = bid >= 192;
  int row0, col0;
  const u16 *A, *Bt;
  int maxRowA, maxRowB;
  if (!isKP) {
    int by = bid / 12, bx = bid - by * 12;
    row0 = by * 256; col0 = bx * 256;
    A = x_bf; Bt = BtQKV; maxRowA = 4095; maxRowB = 3071;
  } else {
    int idx = bid - 192;
    int by = idx >> 2, bx = idx & 3;
    row0 = by * 256; col0 = bx * 256;
    A = pos_bf; Bt = BtKP; maxRowA = 2046; maxRowB = 1023;
  }

  f32x4 acc[8][4];
#pragma unroll
  for (int fi = 0; fi < 8; ++fi)
#pragma unroll
    for (int fj = 0; fj < 4; ++fj) acc[fi][fj] = (f32x4){0.f, 0.f, 0.f, 0.f};

  // prologue: stage tile 0, drain, sync
  stage_tile(A, row0, 0, maxRowA, &As[0][0], tid);
  stage_tile(Bt, col0, 0, maxRowB, &Bs[0][0], tid);
  __syncthreads();

  const int NT = 16;
  for (int t = 0; t < NT; ++t) {
    const int cur = t & 1;
    // issue next tile FIRST -- loads stay in flight under the MFMA phase
    if (t + 1 < NT) {
      stage_tile(A, row0, (t + 1) * 64, maxRowA, &As[cur ^ 1][0], tid);
      stage_tile(Bt, col0, (t + 1) * 64, maxRowB, &Bs[cur ^ 1][0], tid);
    }
    const u16* bufA = &As[cur][0];
    const u16* bufB = &Bs[cur][0];
#pragma unroll
    for (int ks = 0; ks < 2; ++ks) {
      const int pc = ((ks << 2) | lg) ^ (lc & 7);        // swizzled read chunk
      const u16* pA = bufA + (wr * 128 + lc) * 64 + pc * 8;
      const u16* pB = bufB + (wc * 64 + lc) * 64 + pc * 8;
      bf16x8 af[8], bfr[4];
#pragma unroll
      for (int fi = 0; fi < 8; ++fi)
        af[fi] = *reinterpret_cast<const bf16x8*>(pA + fi * 1024);
#pragma unroll
      for (int fj = 0; fj < 4; ++fj)
        bfr[fj] = *reinterpret_cast<const bf16x8*>(pB + fj * 1024);
#pragma unroll
      for (int fi = 0; fi < 8; ++fi)
#pragma unroll
        for (int fj = 0; fj < 4; ++fj)
          acc[fi][fj] = __builtin_amdgcn_mfma_f32_16x16x32_bf16(
              af[fi], bfr[fj], acc[fi][fj], 0, 0, 0);
    }
    // single barrier: drains vmcnt(0) (tile t+1 landed during MFMA) and
    // guarantees all waves' ds_reads of buf[cur] done before next overwrite
    __syncthreads();
  }

#pragma unroll
  for (int fi = 0; fi < 8; ++fi)
#pragma unroll
    for (int fj = 0; fj < 4; ++fj)
#pragma unroll
      for (int reg = 0; reg < 4; ++reg) {
        int R = row0 + wr * 128 + fi * 16 + lg * 4 + reg;
        int C = col0 + wc * 64 + fj * 16 + lc;
        float val = acc[fi][fj][reg];
        if (isKP) {
          if (R < 2047) {
            int hh = C >> 6, ss = C & 63;
            kp[((size_t)hh * 2047 + R) * 64 + ss] = f2bf(val);
          }
        } else {
          int wsel = C >> 10, Cl = C & 1023;
          int bi = R >> 10, tt = R & 1023, hh = Cl >> 6, ss = Cl & 63;
          size_t o = ((size_t)(bi * 16 + hh) << 16) + (size_t)tt * 64 + ss;
          if (wsel == 0) {
            qa[o] = f2bf(val + parma[Cl]);
            qb[o] = f2bf(val + parmb[Cl]);
          } else if (wsel == 1) {
            kb[o] = f2bf(val);
          } else {
            vb[o] = f2bf(val);
          }
        }
      }
}

// ---------------------------------------------------------------------------
// Output projection: out(4096x1024 fp32) = ctx @ Wu + bu. (unchanged)
// ---------------------------------------------------------------------------
__global__ __launch_bounds__(512, 2) void gemm_out(
    const u16* __restrict__ A, const u16* __restrict__ Bt,
    float* __restrict__ outF, const float* __restrict__ bias) {
  __shared__ u16 As[128 * 64];
  __shared__ u16 Bs[128 * 64];
  const int tid = threadIdx.x;
  const int w = tid >> 6, l = tid & 63;
  const int lg = l >> 4, lc = l & 15;
  const int wr = w >> 2, wc = w & 3;
  const int row0 = blockIdx.y * 128;
  const int col0 = blockIdx.x * 128;

  f32x4 acc[4][2];
#pragma unroll
  for (int fi = 0; fi < 4; ++fi)
#pragma unroll
    for (int fj = 0; fj < 2; ++fj) acc[fi][fj] = (f32x4){0.f, 0.f, 0.f, 0.f};

  for (int kbk = 0; kbk < 1024; kbk += 64) {
#pragma unroll
    for (int it2 = 0; it2 < 2; ++it2) {
      int seg = w * 2 + it2;
      int r = seg * 8 + (l >> 3);
      int c8 = (l & 7) * 8;
      async_copy16(&A[(size_t)(row0 + r) * 1024 + kbk + c8], &As[seg * 512]);
      async_copy16(&Bt[(size_t)(col0 + r) * 1024 + kbk + c8], &Bs[seg * 512]);
    }
    __syncthreads();
#pragma unroll
    for (int ks = 0; ks < 2; ++ks) {
      bf16x8 af[4], bfr[2];
#pragma unroll
      for (int fi = 0; fi < 4; ++fi)
        af[fi] = *reinterpret_cast<const bf16x8*>(
            &As[(wr * 64 + fi * 16 + lc) * 64 + ks * 32 + lg * 8]);
#pragma unroll
      for (int fj = 0; fj < 2; ++fj)
        bfr[fj] = *reinterpret_cast<const bf16x8*>(
            &Bs[(wc * 32 + fj * 16 + lc) * 64 + ks * 32 + lg * 8]);
#pragma unroll
      for (int fi = 0; fi < 4; ++fi)
#pragma unroll
        for (int fj = 0; fj < 2; ++fj)
          acc[fi][fj] = __builtin_amdgcn_mfma_f32_16x16x32_bf16(
              af[fi], bfr[fj], acc[fi][fj], 0, 0, 0);
    }
    __syncthreads();
  }

#pragma unroll
  for (int fi = 0; fi < 4; ++fi)
#pragma unroll
    for (int fj = 0; fj < 2; ++fj)
#pragma unroll
      for (int reg = 0; reg < 4; ++reg) {
        int R = row0 + wr * 64 + fi * 16 + lg * 4 + reg;
        int C = col0 + wc * 32 + fj * 16 + lc;
        outF[(size_t)R * 1024 + C] = acc[fi][fj][reg] + bias[C];
      }
}

// ---------------------------------------------------------------------------
// MFMA flash attention, QBLK=128 / 8 waves / KBLK=64. (unchanged)
// ---------------------------------------------------------------------------
__global__ __launch_bounds__(512, 2) void attn_mfma(
    const u16* __restrict__ qa_g, const u16* __restrict__ qb_g,
    const u16* __restrict__ k_g, const u16* __restrict__ v_g,
    const u16* __restrict__ kp_g, u16* __restrict__ ctx) {
  __shared__ u16 kT[64 * 72];      // k tile [j][s]
  __shared__ u16 vT[64 * 72];      // v transposed [s][j]
  __shared__ u16 kpl[192 * 72];    // kp window [d][s]
  __shared__ float G[8][16 * 81];  // per-wave banded scores (stride 81)
  __shared__ u16 P[8][16 * 72];    // per-wave P tile [r][j]

  const int tid = threadIdx.x;
  const int w = tid >> 6, l = tid & 63;
  const int lg = l >> 4, lc = l & 15;
  const int bh = blockIdx.x;
  const int h = bh & 15;
  const int i0 = (7 - (int)blockIdx.y) * 128;   // longest blocks first
  const size_t bhOff = (size_t)bh << 16;
  const size_t hOff = (size_t)h * 2047 * 64;

  // persistent A-fragments: qa/qb rows i0 + w*16 + lc
  bf16x8 qaf[2], qbf[2];
#pragma unroll
  for (int ks = 0; ks < 2; ++ks) {
    size_t o = bhOff + (size_t)(i0 + w * 16 + lc) * 64 + ks * 32 + lg * 8;
    qaf[ks] = *reinterpret_cast<const bf16x8*>(&qa_g[o]);
    qbf[ks] = *reinterpret_cast<const bf16x8*>(&qb_g[o]);
  }

  // prefetch tile 0 into regs
  const int k_j = tid >> 3, k_c8 = (tid & 7) * 8;   // k/kp chunk coords
  const int v_j = tid & 63, v_s0 = (tid >> 6) * 8;  // v transpose coords
  u16x8 pk, pv, pp[3];
  {
    pk = *reinterpret_cast<const u16x8*>(&k_g[bhOff + (size_t)k_j * 64 + k_c8]);
    pv = *reinterpret_cast<const u16x8*>(&v_g[bhOff + (size_t)v_j * 64 + v_s0]);
#pragma unroll
    for (int r = 0; r < 3; ++r) {
      int idx = tid + r * 512;
      int d = idx >> 3, c8 = (idx & 7) * 8;
      int p = i0 + d; if (p > 2046) p = 2046;
      pp[r] = *reinterpret_cast<const u16x8*>(&kp_g[hOff + (size_t)p * 64 + c8]);
    }
  }

  f32x4 O[4];
  float m_r[4], l_r[4];
#pragma unroll
  for (int fj = 0; fj < 4; ++fj) O[fj] = (f32x4){0.f, 0.f, 0.f, 0.f};
#pragma unroll
  for (int reg = 0; reg < 4; ++reg) { m_r[reg] = NEG_INF_F; l_r[reg] = 0.f; }

  const int nt = (i0 >> 6) + 2;
  for (int jt = 0; jt < nt; ++jt) {
    const int j0 = jt * 64;
    __syncthreads();   // previous tile's LDS reads complete
    // write staged regs to LDS
    *reinterpret_cast<u16x8*>(&kT[k_j * 72 + k_c8]) = pk;
#pragma unroll
    for (int i2 = 0; i2 < 8; ++i2) vT[(v_s0 + i2) * 72 + v_j] = pv[i2];
#pragma unroll
    for (int r = 0; r < 3; ++r) {
      int idx = tid + r * 512;
      int d = idx >> 3, c8 = (idx & 7) * 8;
      *reinterpret_cast<u16x8*>(&kpl[d * 72 + c8]) = pp[r];
    }
    __syncthreads();
    // prefetch next tile (latency hides under compute below)
    if (jt + 1 < nt) {
      const int jn = j0 + 64, pbn = i0 + jn;
      pk = *reinterpret_cast<const u16x8*>(
          &k_g[bhOff + (size_t)(jn + k_j) * 64 + k_c8]);
      pv = *reinterpret_cast<const u16x8*>(
          &v_g[bhOff + (size_t)(jn + v_j) * 64 + v_s0]);
#pragma unroll
      for (int r = 0; r < 3; ++r) {
        int idx = tid + r * 512;
        int d = idx >> 3, c8 = (idx & 7) * 8;
        int p = pbn + d; if (p > 2046) p = 2046;
        pp[r] = *reinterpret_cast<const u16x8*>(&kp_g[hOff + (size_t)p * 64 + c8]);
      }
    }
    // fully-masked waves skip compute (still hit barriers next iter)
    if (j0 > i0 + w * 16 + 15) continue;

    f32x4 S[4], Gf[5];
#pragma unroll
    for (int fj = 0; fj < 4; ++fj) S[fj] = (f32x4){0.f, 0.f, 0.f, 0.f};
#pragma unroll
    for (int fg = 0; fg < 5; ++fg) Gf[fg] = (f32x4){0.f, 0.f, 0.f, 0.f};
#pragma unroll
    for (int ks = 0; ks < 2; ++ks) {
#pragma unroll
      for (int fj = 0; fj < 4; ++fj) {
        bf16x8 kf = *reinterpret_cast<const bf16x8*>(
            &kT[(fj * 16 + lc) * 72 + ks * 32 + lg * 8]);
        S[fj] = __builtin_amdgcn_mfma_f32_16x16x32_bf16(qaf[ks], kf, S[fj], 0, 0, 0);
      }
#pragma unroll
      for (int fg = 0; fg < 5; ++fg) {
        bf16x8 pf = *reinterpret_cast<const bf16x8*>(
            &kpl[((w + fg) * 16 + lc) * 72 + ks * 32 + lg * 8]);
        Gf[fg] = __builtin_amdgcn_mfma_f32_16x16x32_bf16(qbf[ks], pf, Gf[fg], 0, 0, 0);
      }
    }
    // per-wave G spill (stride 81 -> <=2-way banks)
    float* Gw = G[w];
#pragma unroll
    for (int fg = 0; fg < 5; ++fg)
#pragma unroll
      for (int reg = 0; reg < 4; ++reg)
        Gw[(lg * 4 + reg) * 81 + fg * 16 + lc] = Gf[fg][reg];
    asm volatile("s_waitcnt lgkmcnt(0)" ::: "memory");
    __builtin_amdgcn_sched_barrier(0);
    // skew gather + causal mask
    const bool needMask = (j0 + 63 > i0 + w * 16);
#pragma unroll
    for (int fj = 0; fj < 4; ++fj)
#pragma unroll
      for (int reg = 0; reg < 4; ++reg) {
        int rf = lg * 4 + reg;
        float sv = S[fj][reg] + Gw[rf * 81 + rf + fj * 16 + lc];
        if (needMask && (i0 + w * 16 + rf) < (j0 + fj * 16 + lc)) sv = NEG_INF_F;
        S[fj][reg] = sv;
      }
    // online softmax (16-lane row groups)
#pragma unroll
    for (int reg = 0; reg < 4; ++reg) {
      float mx = fmaxf(fmaxf(S[0][reg], S[1][reg]), fmaxf(S[2][reg], S[3][reg]));
      mx = fmaxf(mx, __shfl_xor(mx, 1));
      mx = fmaxf(mx, __shfl_xor(mx, 2));
      mx = fmaxf(mx, __shfl_xor(mx, 4));
      mx = fmaxf(mx, __shfl_xor(mx, 8));
      float mnew = fmaxf(m_r[reg], mx);
      float corr = __expf(m_r[reg] - mnew);
      float rs = 0.f;
#pragma unroll
      for (int fj = 0; fj < 4; ++fj) {
        float p = __expf(S[fj][reg] - mnew);
        S[fj][reg] = p;
        rs += p;
      }
      rs += __shfl_xor(rs, 1); rs += __shfl_xor(rs, 2);
      rs += __shfl_xor(rs, 4); rs += __shfl_xor(rs, 8);
      l_r[reg] = l_r[reg] * corr + rs;
      m_r[reg] = mnew;
#pragma unroll
      for (int fj = 0; fj < 4; ++fj) O[fj][reg] *= corr;
    }
    // per-wave P spill (no barrier needed)
    u16* Pw = P[w];
#pragma unroll
    for (int fj = 0; fj < 4; ++fj)
#pragma unroll
      for (int reg = 0; reg < 4; ++reg)
        Pw[(lg * 4 + reg) * 72 + fj * 16 + lc] = f2bf(S[fj][reg]);
    asm volatile("s_waitcnt lgkmcnt(0)" ::: "memory");
    __builtin_amdgcn_sched_barrier(0);
    // PV: O += P @ V
#pragma unroll
    for (int ks = 0; ks < 2; ++ks) {
      bf16x8 pa = *reinterpret_cast<const bf16x8*>(&Pw[lc * 72 + ks * 32 + lg * 8]);
#pragma unroll
      for (int fj = 0; fj < 4; ++fj) {
        bf16x8 vb = *reinterpret_cast<const bf16x8*>(
            &vT[(fj * 16 + lc) * 72 + ks * 32 + lg * 8]);
        O[fj] = __builtin_amdgcn_mfma_f32_16x16x32_bf16(pa, vb, O[fj], 0, 0, 0);
      }
    }
  }

  // normalize + write ctx (b, t, e) as bf16
  const int b = bh >> 4;
#pragma unroll
  for (int reg = 0; reg < 4; ++reg) {
    float inv = 1.f / l_r[reg];
    int r = w * 16 + lg * 4 + reg;
#pragma unroll
    for (int fj = 0; fj < 4; ++fj)
      ctx[((size_t)b * 1024 + i0 + r) * 1024 + h * 64 + fj * 16 + lc] =
          f2bf(O[fj][reg] * inv);
  }
}

// ---------------------------------------------------------------------------
extern "C" void kernel_launch(void* const* d_in, const int* in_sizes, int n_in,
                              void* d_out, int out_size, void* d_ws, size_t ws_size,
                              hipStream_t stream) {
  const float* x       = (const float*)d_in[0];
  const float* Wq      = (const float*)d_in[1];
  const float* Wk      = (const float*)d_in[2];
  const float* Wkp     = (const float*)d_in[3];
  const float* Wv      = (const float*)d_in[4];
  const float* Wu      = (const float*)d_in[5];
  const float* bu      = (const float*)d_in[6];
  const float* parma   = (const float*)d_in[7];   // flat (h*s) = 1024
  const float* parmb   = (const float*)d_in[8];
  const float* pos_emb = (const float*)d_in[9];   // (2047, 1024)
  float* out = (float*)d_out;

  // workspace (u16 elements); wqT/wkT/wvT contiguous => fused QKV B-matrix
  u16* W = (u16*)d_ws;
  u16* x_bf   = W;                      // 4194304
  u16* pos_bf = x_bf + 4194304;         // 2096128
  u16* wqT    = pos_bf + 2096128;       // 1048576 each
  u16* wkT    = wqT + 1048576;
  u16* wvT    = wkT + 1048576;
  u16* wkpT   = wvT + 1048576;
  u16* wuT    = wkpT + 1048576;
  u16* qa     = wuT + 1048576;          // 4194304 (b,h,t,s)
  u16* qb     = qa + 4194304;
  u16* kb     = qb + 4194304;
  u16* vb     = kb + 4194304;
  u16* kp     = vb + 4194304;           // 2096128 (h,p,s)
  u16* ctx    = kp + 2096128;           // 4194304 (b,t,e)

  // conversions
  cvt_bf16<<<4096, 256, 0, stream>>>(x, x_bf, 1048576);
  cvt_bf16<<<2047, 256, 0, stream>>>(pos_emb, pos_bf, 524032);
  cvt_w_tr<<<dim3(16, 16, 5), 256, 0, stream>>>(Wq, Wk, Wkp, Wv, Wu,
                                                wqT, wkT, wkpT, wvT, wuT);
  // fused QKV + KP projections (256^2 tiles, 224 blocks, 1/CU)
  gemm_qkvp<<<224, 512, 0, stream>>>(x_bf, pos_bf, wqT, wkpT,
                                     qa, qb, kb, vb, kp, parma, parmb);
  // attention
  attn_mfma<<<dim3(64, 8), 512, 0, stream>>>(qa, qb, kb, vb, kp, ctx);
  // out = ctx @ Wu + bu
  gemm_out<<<dim3(8, 32), 512, 0, stream>>>(ctx, wuT, out, bu);
}